// Round 4
// baseline (108.425 us; speedup 1.0000x reference)
//
#include <hip/hip_runtime.h>

// EntityAttention — round 4: 2 waves/SIMD in all GEMM stages + launch fusion.
// NB=8 SL=512 NH=512 EN=16 NE=64 HEADS=2 DH=256. Selection masks all-True.

#define NB 8
#define SL 512
#define NH 512
#define EN 16
#define NE 64
#define HEADS 2
#define DH 256
#define NSLOT (NB * EN)
#define SCALE 0.0625f

typedef __attribute__((ext_vector_type(8))) short short8;
typedef __attribute__((ext_vector_type(4))) short short4v;
typedef __attribute__((ext_vector_type(4))) float f32x4;

#define MFMA16(a, b, c) __builtin_amdgcn_mfma_f32_16x16x32_bf16(a, b, c, 0, 0, 0)

__device__ __forceinline__ short f2b(float f) {
    unsigned u = __builtin_bit_cast(unsigned, f);
    u += 0x7fffu + ((u >> 16) & 1u);
    return (short)(u >> 16);
}

// ---- ws byte offsets (ws = 256 MiB; no aliasing) ---------------------------
#define WS_TOKS 0u
#define WS_K (4u << 20)
#define WS_VT (8u << 20)
#define WS_CTX (12u << 20)
#define WS_S (20u << 20)
#define WS_WK (22u << 20)
#define WS_WV (WS_WK + (512u << 10))
#define WS_WO (WS_WV + (512u << 10))
#define WS_WQ (WS_WO + (512u << 10))
#define WS_EV (WS_WQ + (512u << 10))
#define WS_Q (WS_EV + (64u << 10))
#define WS_FLAG (WS_Q + (64u << 10))

// chunk counts (f32x4 units) for prep
#define CH_TOKS (NB * SL * NH / 4) /* 524288 */
#define CH_W (NH * NH / 4)         /* 65536 */
#define CH_EV (NE * NH / 4)        /* 8192 */
#define CH_TOTAL (CH_TOKS + 4 * CH_W + CH_EV) /* 794624 = 3104*256 */

// ---------------------------------------------------------------------------
// prep: all fp32->bf16 conversions + bool-encoding detection (last block).
__global__ void prep_kernel(const float* __restrict__ toks, const float* __restrict__ Wk,
                            const float* __restrict__ Wv, const float* __restrict__ Wo,
                            const float* __restrict__ Wq, const float* __restrict__ ev,
                            const unsigned char* __restrict__ ents,
                            short* __restrict__ toks_bf, short* __restrict__ Wk_bf,
                            short* __restrict__ Wv_bf, short* __restrict__ Wo_bf,
                            short* __restrict__ Wq_bf, short* __restrict__ ev_bf,
                            int* __restrict__ flag) {
    __shared__ int red[256];
    int idx = blockIdx.x * 256 + threadIdx.x;
    if (idx < CH_TOTAL) {
        const float* src;
        short* dst;
        int off = idx;
        if (idx < CH_TOKS) { src = toks; dst = toks_bf; }
        else if (idx < CH_TOKS + CH_W) { src = Wk; dst = Wk_bf; off -= CH_TOKS; }
        else if (idx < CH_TOKS + 2 * CH_W) { src = Wv; dst = Wv_bf; off -= CH_TOKS + CH_W; }
        else if (idx < CH_TOKS + 3 * CH_W) { src = Wo; dst = Wo_bf; off -= CH_TOKS + 2 * CH_W; }
        else if (idx < CH_TOKS + 4 * CH_W) { src = Wq; dst = Wq_bf; off -= CH_TOKS + 3 * CH_W; }
        else { src = ev; dst = ev_bf; off -= CH_TOKS + 4 * CH_W; }
        f32x4 v = ((const f32x4*)src)[off];
        short4v o;
#pragma unroll
        for (int j = 0; j < 4; ++j) o[j] = f2b(v[j]);
        ((short4v*)dst)[off] = o;
    }
    if (blockIdx.x == gridDim.x - 1) {
        int tid = threadIdx.x;
        int cnt = 0;
        for (int j = 0; j < 16; ++j) {
            int off = tid * 16 + j;
            if ((off & 3) != 0 && ents[off] != 0) cnt++;
        }
        red[tid] = cnt;
        __syncthreads();
        for (int s = 128; s > 0; s >>= 1) {
            if (tid < s) red[tid] += red[tid + s];
            __syncthreads();
        }
        if (tid == 0) flag[0] = (red[0] == 0) ? 1 : 0;
    }
}

// ---------------------------------------------------------------------------
// proj: K, V, and q projections in one kernel. 64x32 wave tiles (4i x 2j).
// t<256: K (128x64 block); t<512: V (transposed out); t>=512: q (4 blocks).
__global__ void proj_kernel(const short* __restrict__ toks_bf,
                            const short* __restrict__ Wk_bf,
                            const short* __restrict__ Wv_bf,
                            const short* __restrict__ ev_bf,
                            const short* __restrict__ Wq_bf,
                            const float* __restrict__ bk, const float* __restrict__ bv,
                            const float* __restrict__ bq,
                            short* __restrict__ K_bf, short* __restrict__ Vt_bf,
                            short* __restrict__ q_bf) {
    int t = blockIdx.x;
    int tid = threadIdx.x, lane = tid & 63, wid = tid >> 6;
    int l15 = lane & 15;
    int kb = (lane >> 4) * 8;

    int kind, m0, n0;
    const short *A, *B;
    const float* bias;
    if (t < 512) {
        kind = t >> 8;
        int tt = t & 255;
        int mt = tt >> 3, nt = tt & 7;
        m0 = mt * 128 + (wid >> 1) * 64;
        n0 = nt * 64 + (wid & 1) * 32;
        A = toks_bf + (size_t)(m0 + l15) * NH + kb;
        B = (kind ? Wv_bf : Wk_bf) + (size_t)(n0 + l15) * NH + kb;
        bias = kind ? bv : bk;
    } else {
        kind = 2;
        int tq = t - 512; // 0..3
        m0 = 0;
        n0 = tq * 128 + wid * 32;
        A = ev_bf + (size_t)l15 * NH + kb;
        B = Wq_bf + (size_t)(n0 + l15) * NH + kb;
        bias = bq;
    }

    f32x4 acc[4][2];
#pragma unroll
    for (int i = 0; i < 4; ++i)
#pragma unroll
        for (int j = 0; j < 2; ++j) acc[i][j] = (f32x4)0.f;

    for (int k = 0; k < NH; k += 32) {
        short8 a[4], bb[2];
#pragma unroll
        for (int i = 0; i < 4; ++i) a[i] = *(const short8*)(A + (size_t)i * 16 * NH + k);
#pragma unroll
        for (int j = 0; j < 2; ++j) bb[j] = *(const short8*)(B + (size_t)j * 16 * NH + k);
#pragma unroll
        for (int i = 0; i < 4; ++i)
#pragma unroll
            for (int j = 0; j < 2; ++j) acc[i][j] = MFMA16(a[i], bb[j], acc[i][j]);
    }

    int crow = (lane >> 4) * 4, ccol = l15;
#pragma unroll
    for (int i = 0; i < 4; ++i) {
#pragma unroll
        for (int j = 0; j < 2; ++j) {
            int col = n0 + j * 16 + ccol;
            float bval = bias[col];
            int row0 = m0 + i * 16 + crow;
            if (kind == 0) {
#pragma unroll
                for (int r = 0; r < 4; ++r)
                    K_bf[(size_t)(row0 + r) * NH + col] = f2b(acc[i][j][r] + bval);
            } else if (kind == 1) {
                int b = row0 >> 9, sr = row0 & 511;
                short4v pack;
#pragma unroll
                for (int r = 0; r < 4; ++r) pack[r] = f2b(acc[i][j][r] + bval);
                *(short4v*)(Vt_bf + ((size_t)b * NH + col) * SL + sr) = pack;
            } else {
#pragma unroll
                for (int r = 0; r < 4; ++r)
                    q_bf[(size_t)(row0 + r) * NH + col] = f2b((acc[i][j][r] + bval) * SCALE);
            }
        }
    }
}

// ---------------------------------------------------------------------------
// scores[b][h][e][s] = q_scaled[e] . K[b][s] (per head). grid (16, 4).
__global__ void scores_mfma(const short* __restrict__ q_bf,
                            const short* __restrict__ K_bf,
                            float* __restrict__ S) {
    int bh = blockIdx.x;
    int b = bh >> 1, h = bh & 1;
    int st = blockIdx.y;
    int tid = threadIdx.x, lane = tid & 63, wid = tid >> 6;
    int n0 = st * 128 + wid * 32;
    int kb = (lane >> 4) * 8;

    f32x4 acc[4][2];
#pragma unroll
    for (int i = 0; i < 4; ++i)
#pragma unroll
        for (int j = 0; j < 2; ++j) acc[i][j] = (f32x4)0.f;

    const short* Aq = q_bf + (size_t)(lane & 15) * NH + h * DH + kb;
    const short* Bk = K_bf + ((size_t)b * SL + n0 + (lane & 15)) * NH + h * DH + kb;
    for (int k = 0; k < DH; k += 32) {
        short8 a[4], bb[2];
#pragma unroll
        for (int i = 0; i < 4; ++i) a[i] = *(const short8*)(Aq + (size_t)i * 16 * NH + k);
#pragma unroll
        for (int j = 0; j < 2; ++j) bb[j] = *(const short8*)(Bk + (size_t)j * 16 * NH + k);
#pragma unroll
        for (int i = 0; i < 4; ++i)
#pragma unroll
            for (int j = 0; j < 2; ++j) acc[i][j] = MFMA16(a[i], bb[j], acc[i][j]);
    }

    int crow = (lane >> 4) * 4, ccol = lane & 15;
#pragma unroll
    for (int i = 0; i < 4; ++i)
#pragma unroll
        for (int j = 0; j < 2; ++j) {
            int col = n0 + j * 16 + ccol;
#pragma unroll
            for (int r = 0; r < 4; ++r) {
                int row = i * 16 + crow + r;
                S[(((size_t)(b * HEADS + h)) * NE + row) * SL + col] = acc[i][j][r];
            }
        }
}

// ---------------------------------------------------------------------------
// Fused mask -> softmax -> PV. 512 threads (8 waves) per (slot n, head h).
// Softmax: wave w owns rows w*8..w*8+7. PV: wave = (ehalf, d-quad).
__global__ void softmax_pv(const float* __restrict__ S,
                           const short* __restrict__ Vt_bf,
                           const void* __restrict__ ents,
                           const int* __restrict__ flag,
                           short* __restrict__ ctx_bf) {
    __shared__ short Plds[NE * SL]; // 64 KB
    int n = blockIdx.x, h = blockIdx.y;
    int b = n >> 4, ent = n & 15;
    int tid = threadIdx.x, lane = tid & 63, wid = tid >> 6;

    unsigned att8 = 0;
    {
        size_t mbase = ((size_t)b * EN + ent) * SL + lane * 8;
        if (flag[0]) {
            const int* p = (const int*)ents;
#pragma unroll
            for (int j = 0; j < 8; ++j)
                if (p[mbase + j]) att8 |= 1u << j;
        } else {
            const unsigned char* p = (const unsigned char*)ents;
#pragma unroll
            for (int j = 0; j < 8; ++j)
                if (p[mbase + j]) att8 |= 1u << j;
        }
    }

    for (int it = 0; it < 8; ++it) {
        int e = wid * 8 + it;
        const float* srow = S + (((size_t)(b * HEADS + h)) * NE + e) * SL + lane * 8;
        f32x4 s0 = *(const f32x4*)(srow);
        f32x4 s1 = *(const f32x4*)(srow + 4);
        float v[8];
#pragma unroll
        for (int j = 0; j < 4; ++j) v[j] = (att8 >> j & 1) ? s0[j] : -1e9f;
#pragma unroll
        for (int j = 0; j < 4; ++j) v[4 + j] = (att8 >> (4 + j) & 1) ? s1[j] : -1e9f;
        float m = v[0];
#pragma unroll
        for (int j = 1; j < 8; ++j) m = fmaxf(m, v[j]);
        for (int off = 32; off; off >>= 1) m = fmaxf(m, __shfl_xor(m, off));
        float p[8], sum = 0.f;
#pragma unroll
        for (int j = 0; j < 8; ++j) {
            p[j] = expf(v[j] - m);
            sum += p[j];
        }
        for (int off = 32; off; off >>= 1) sum += __shfl_xor(sum, off);
        float inv = 1.f / sum;
        short8 pv;
#pragma unroll
        for (int j = 0; j < 8; ++j) pv[j] = f2b(p[j] * inv);
        *(short8*)&Plds[e * SL + ((lane ^ (e & 7)) * 8)] = pv;
    }
    __syncthreads();

    // PV: wave = (ehalf, dquad): rows e0..e0+31, cols n0..n0+63 of this head.
    int e0 = (wid >> 2) * 32;
    int n0 = (wid & 3) * 64;
    int l15 = lane & 15;
    int kb = (lane >> 4) * 8;
    f32x4 acc[2][4];
#pragma unroll
    for (int i = 0; i < 2; ++i)
#pragma unroll
        for (int j = 0; j < 4; ++j) acc[i][j] = (f32x4)0.f;

    const short* Bv = Vt_bf + ((size_t)b * NH + h * DH + n0 + l15) * SL + kb;
    for (int k = 0; k < SL; k += 32) {
        int g = (k + kb) >> 3;
        short8 a[2], bb[4];
#pragma unroll
        for (int i = 0; i < 2; ++i) {
            int e = e0 + i * 16 + l15;
            a[i] = *(const short8*)&Plds[e * SL + ((g ^ (e & 7)) * 8)];
        }
#pragma unroll
        for (int j = 0; j < 4; ++j) bb[j] = *(const short8*)(Bv + (size_t)j * 16 * SL + k);
#pragma unroll
        for (int i = 0; i < 2; ++i)
#pragma unroll
            for (int j = 0; j < 4; ++j) acc[i][j] = MFMA16(a[i], bb[j], acc[i][j]);
    }

    int crow = (lane >> 4) * 4, ccol = l15;
#pragma unroll
    for (int i = 0; i < 2; ++i)
#pragma unroll
        for (int j = 0; j < 4; ++j) {
            int col = h * DH + n0 + j * 16 + ccol;
#pragma unroll
            for (int r = 0; r < 4; ++r) {
                int row = e0 + i * 16 + crow + r;
                ctx_bf[((size_t)n * NE + row) * NH + col] = f2b(acc[i][j][r]);
            }
        }
}

// ---------------------------------------------------------------------------
// out = ctx_bf @ Wo^T + bo. 128x64 blocks, 64x32 wave tiles. grid (64, 8).
__global__ void out_mfma(const short* __restrict__ ctx_bf,
                         const short* __restrict__ Wo_bf,
                         const float* __restrict__ bo,
                         float* __restrict__ out) {
    int mt = blockIdx.x, nt = blockIdx.y;
    int tid = threadIdx.x, lane = tid & 63, wid = tid >> 6;
    int l15 = lane & 15;
    int m0 = mt * 128 + (wid >> 1) * 64;
    int n0 = nt * 64 + (wid & 1) * 32;
    int kb = (lane >> 4) * 8;

    f32x4 acc[4][2];
#pragma unroll
    for (int i = 0; i < 4; ++i)
#pragma unroll
        for (int j = 0; j < 2; ++j) acc[i][j] = (f32x4)0.f;

    const short* A = ctx_bf + (size_t)(m0 + l15) * NH + kb;
    const short* B = Wo_bf + (size_t)(n0 + l15) * NH + kb;
    for (int k = 0; k < NH; k += 32) {
        short8 a[4], bb[2];
#pragma unroll
        for (int i = 0; i < 4; ++i) a[i] = *(const short8*)(A + (size_t)i * 16 * NH + k);
#pragma unroll
        for (int j = 0; j < 2; ++j) bb[j] = *(const short8*)(B + (size_t)j * 16 * NH + k);
#pragma unroll
        for (int i = 0; i < 4; ++i)
#pragma unroll
            for (int j = 0; j < 2; ++j) acc[i][j] = MFMA16(a[i], bb[j], acc[i][j]);
    }

    int crow = (lane >> 4) * 4, ccol = l15;
#pragma unroll
    for (int i = 0; i < 4; ++i)
#pragma unroll
        for (int j = 0; j < 2; ++j) {
            int col = n0 + j * 16 + ccol;
            float bval = bo[col];
#pragma unroll
            for (int r = 0; r < 4; ++r) {
                int row = m0 + i * 16 + crow + r;
                out[(size_t)row * NH + col] = acc[i][j][r] + bval;
            }
        }
}

// ---------------------------------------------------------------------------
extern "C" void kernel_launch(void* const* d_in, const int* in_sizes, int n_in,
                              void* d_out, int out_size, void* d_ws, size_t ws_size,
                              hipStream_t stream) {
    const float* toks = (const float*)d_in[0];
    const void* ents = d_in[1];
    const float* evs = (const float*)d_in[2];
    const float* Wq = (const float*)d_in[6];
    const float* Wk = (const float*)d_in[7];
    const float* Wv = (const float*)d_in[8];
    const float* bq = (const float*)d_in[9];
    const float* bk = (const float*)d_in[10];
    const float* bv = (const float*)d_in[11];
    const float* Wo = (const float*)d_in[12];
    const float* bo = (const float*)d_in[13];

    char* ws = (char*)d_ws;
    short* toks_bf = (short*)(ws + WS_TOKS);
    short* K_bf = (short*)(ws + WS_K);
    short* Vt_bf = (short*)(ws + WS_VT);
    short* ctx_bf = (short*)(ws + WS_CTX);
    float* S = (float*)(ws + WS_S);
    short* Wk_bf = (short*)(ws + WS_WK);
    short* Wv_bf = (short*)(ws + WS_WV);
    short* Wo_bf = (short*)(ws + WS_WO);
    short* Wq_bf = (short*)(ws + WS_WQ);
    short* ev_bf = (short*)(ws + WS_EV);
    short* q_bf = (short*)(ws + WS_Q);
    int* flag = (int*)(ws + WS_FLAG);

    prep_kernel<<<CH_TOTAL / 256 + 1, 256, 0, stream>>>(
        toks, Wk, Wv, Wo, Wq, evs, (const unsigned char*)ents,
        toks_bf, Wk_bf, Wv_bf, Wo_bf, Wq_bf, ev_bf, flag);
    proj_kernel<<<516, 256, 0, stream>>>(toks_bf, Wk_bf, Wv_bf, ev_bf, Wq_bf,
                                         bk, bv, bq, K_bf, Vt_bf, q_bf);
    scores_mfma<<<dim3(NB * HEADS, 4), 256, 0, stream>>>(q_bf, K_bf, S);
    softmax_pv<<<dim3(NSLOT, HEADS), 512, 0, stream>>>(S, Vt_bf, ents, flag, ctx_bf);
    out_mfma<<<dim3(64, 8), 256, 0, stream>>>(ctx_bf, Wo_bf, bo, (float*)d_out);
}

// Round 6
// 101.445 us; speedup vs baseline: 1.0688x; 1.0688x over previous
//
#include <hip/hip_runtime.h>

// EntityAttention — round 6: R5 (fused scores/softmax/PV) with proj grid fix.
// NB=8 SL=512 NH=512 EN=16 NE=64 HEADS=2 DH=256. Selection masks all-True.

#define NB 8
#define SL 512
#define NH 512
#define EN 16
#define NE 64
#define HEADS 2
#define DH 256
#define NSLOT (NB * EN)
#define SCALE 0.0625f

typedef __attribute__((ext_vector_type(8))) short short8;
typedef __attribute__((ext_vector_type(4))) short short4v;
typedef __attribute__((ext_vector_type(4))) float f32x4;

#define MFMA16(a, b, c) __builtin_amdgcn_mfma_f32_16x16x32_bf16(a, b, c, 0, 0, 0)

__device__ __forceinline__ short f2b(float f) {
    unsigned u = __builtin_bit_cast(unsigned, f);
    u += 0x7fffu + ((u >> 16) & 1u);
    return (short)(u >> 16);
}
__device__ __forceinline__ float b2f(short s) {
    return __builtin_bit_cast(float, ((unsigned)(unsigned short)s) << 16);
}

// ---- ws byte offsets (no aliasing) -----------------------------------------
#define WS_TOKS 0u
#define WS_K (4u << 20)
#define WS_VT (8u << 20)
#define WS_CTX (12u << 20)
#define WS_WK (22u << 20)
#define WS_WV (WS_WK + (512u << 10))
#define WS_WO (WS_WV + (512u << 10))
#define WS_WQ (WS_WO + (512u << 10))
#define WS_EV (WS_WQ + (512u << 10))
#define WS_Q (WS_EV + (64u << 10))
#define WS_FLAG (WS_Q + (64u << 10))

// chunk counts (f32x4 units) for prep
#define CH_TOKS (NB * SL * NH / 4) /* 524288 */
#define CH_W (NH * NH / 4)         /* 65536 */
#define CH_EV (NE * NH / 4)        /* 8192 */
#define CH_TOTAL (CH_TOKS + 4 * CH_W + CH_EV) /* 794624 */

// ---------------------------------------------------------------------------
// prep: all fp32->bf16 conversions + bool-encoding detection (last block).
__global__ void prep_kernel(const float* __restrict__ toks, const float* __restrict__ Wk,
                            const float* __restrict__ Wv, const float* __restrict__ Wo,
                            const float* __restrict__ Wq, const float* __restrict__ ev,
                            const unsigned char* __restrict__ ents,
                            short* __restrict__ toks_bf, short* __restrict__ Wk_bf,
                            short* __restrict__ Wv_bf, short* __restrict__ Wo_bf,
                            short* __restrict__ Wq_bf, short* __restrict__ ev_bf,
                            int* __restrict__ flag) {
    __shared__ int red[256];
    int idx = blockIdx.x * 256 + threadIdx.x;
    if (idx < CH_TOTAL) {
        const float* src;
        short* dst;
        int off = idx;
        if (idx < CH_TOKS) { src = toks; dst = toks_bf; }
        else if (idx < CH_TOKS + CH_W) { src = Wk; dst = Wk_bf; off -= CH_TOKS; }
        else if (idx < CH_TOKS + 2 * CH_W) { src = Wv; dst = Wv_bf; off -= CH_TOKS + CH_W; }
        else if (idx < CH_TOKS + 3 * CH_W) { src = Wo; dst = Wo_bf; off -= CH_TOKS + 2 * CH_W; }
        else if (idx < CH_TOKS + 4 * CH_W) { src = Wq; dst = Wq_bf; off -= CH_TOKS + 3 * CH_W; }
        else { src = ev; dst = ev_bf; off -= CH_TOKS + 4 * CH_W; }
        f32x4 v = ((const f32x4*)src)[off];
        short4v o;
#pragma unroll
        for (int j = 0; j < 4; ++j) o[j] = f2b(v[j]);
        ((short4v*)dst)[off] = o;
    }
    if (blockIdx.x == gridDim.x - 1) {
        int tid = threadIdx.x;
        int cnt = 0;
        for (int j = 0; j < 16; ++j) {
            int off = tid * 16 + j;
            if ((off & 3) != 0 && ents[off] != 0) cnt++;
        }
        red[tid] = cnt;
        __syncthreads();
        for (int s = 128; s > 0; s >>= 1) {
            if (tid < s) red[tid] += red[tid + s];
            __syncthreads();
        }
        if (tid == 0) flag[0] = (red[0] == 0) ? 1 : 0;
    }
}

// ---------------------------------------------------------------------------
// proj: t<128: K tiles; 128<=t<256: V tiles; t>=256 (4 blocks): q projection.
// K/V: 128x128 block tile, 4 waves of 64x64 (4x4 frags).
__global__ void proj_kernel(const short* __restrict__ toks_bf,
                            const short* __restrict__ Wk_bf,
                            const short* __restrict__ Wv_bf,
                            const short* __restrict__ ev_bf,
                            const short* __restrict__ Wq_bf,
                            const float* __restrict__ bk, const float* __restrict__ bv,
                            const float* __restrict__ bq,
                            short* __restrict__ K_bf, short* __restrict__ Vt_bf,
                            short* __restrict__ q_bf) {
    int t = blockIdx.x;
    int tid = threadIdx.x, lane = tid & 63, wid = tid >> 6;
    int l15 = lane & 15;
    int kb = (lane >> 4) * 8;
    int crow = (lane >> 4) * 4;

    if (t < 256) {
        int kind = t >> 7;        // 0 = K, 1 = V
        int tt = t & 127;         // 0..127
        int b = tt >> 4, mt = (tt >> 2) & 3, nt = tt & 3; // b in 0..7
        int m0 = mt * 128 + (wid >> 1) * 64;
        int n0 = nt * 128 + (wid & 1) * 64;
        const short* A = toks_bf + ((size_t)b * SL + m0 + l15) * NH + kb;
        const short* B = (kind ? Wv_bf : Wk_bf) + (size_t)(n0 + l15) * NH + kb;
        const float* bias = kind ? bv : bk;

        f32x4 acc[4][4];
#pragma unroll
        for (int i = 0; i < 4; ++i)
#pragma unroll
            for (int j = 0; j < 4; ++j) acc[i][j] = (f32x4)0.f;

        for (int k = 0; k < NH; k += 32) {
            short8 a[4], bb[4];
#pragma unroll
            for (int i = 0; i < 4; ++i) a[i] = *(const short8*)(A + (size_t)i * 16 * NH + k);
#pragma unroll
            for (int j = 0; j < 4; ++j) bb[j] = *(const short8*)(B + (size_t)j * 16 * NH + k);
#pragma unroll
            for (int i = 0; i < 4; ++i)
#pragma unroll
                for (int j = 0; j < 4; ++j) acc[i][j] = MFMA16(a[i], bb[j], acc[i][j]);
        }

#pragma unroll
        for (int i = 0; i < 4; ++i) {
#pragma unroll
            for (int j = 0; j < 4; ++j) {
                int col = n0 + j * 16 + l15;
                float bval = bias[col];
                int row0 = m0 + i * 16 + crow;
                if (kind == 0) {
#pragma unroll
                    for (int r = 0; r < 4; ++r)
                        K_bf[((size_t)b * SL + row0 + r) * NH + col] = f2b(acc[i][j][r] + bval);
                } else {
                    short4v pack;
#pragma unroll
                    for (int r = 0; r < 4; ++r) pack[r] = f2b(acc[i][j][r] + bval);
                    *(short4v*)(Vt_bf + ((size_t)b * NH + col) * SL + row0) = pack;
                }
            }
        }
    } else {
        // q projection: M=64, N=512 over 4 blocks; wave = 64e x 32cols.
        int tq = t - 256; // 0..3
        int n0 = tq * 128 + wid * 32;
        const short* A = ev_bf + (size_t)l15 * NH + kb;
        const short* B = Wq_bf + (size_t)(n0 + l15) * NH + kb;

        f32x4 acc[4][2];
#pragma unroll
        for (int i = 0; i < 4; ++i)
#pragma unroll
            for (int j = 0; j < 2; ++j) acc[i][j] = (f32x4)0.f;

        for (int k = 0; k < NH; k += 32) {
            short8 a[4], bb[2];
#pragma unroll
            for (int i = 0; i < 4; ++i) a[i] = *(const short8*)(A + (size_t)i * 16 * NH + k);
#pragma unroll
            for (int j = 0; j < 2; ++j) bb[j] = *(const short8*)(B + (size_t)j * 16 * NH + k);
#pragma unroll
            for (int i = 0; i < 4; ++i)
#pragma unroll
                for (int j = 0; j < 2; ++j) acc[i][j] = MFMA16(a[i], bb[j], acc[i][j]);
        }

#pragma unroll
        for (int i = 0; i < 4; ++i)
#pragma unroll
            for (int j = 0; j < 2; ++j) {
                int col = n0 + j * 16 + l15;
                float bval = bq[col];
#pragma unroll
                for (int r = 0; r < 4; ++r)
                    q_bf[(size_t)(i * 16 + crow + r) * NH + col] = f2b((acc[i][j][r] + bval) * SCALE);
            }
    }
}

// ---------------------------------------------------------------------------
// Fused scores -> mask -> softmax -> PV. Block = (slot n, head h), 512 thr.
// One 64 KB LDS buffer holds S (bf16) then P (bf16) in the same swizzled
// layout: element (e, s) at short index e*SL + ((s>>3 ^ (e&7))*8) + (s&7).
__global__ void fused_attn(const short* __restrict__ q_bf,
                           const short* __restrict__ K_bf,
                           const short* __restrict__ Vt_bf,
                           const void* __restrict__ ents,
                           const int* __restrict__ flag,
                           short* __restrict__ ctx_bf) {
    __shared__ short Pld[NE * SL]; // 64 KB
    int n = blockIdx.x, h = blockIdx.y;
    int b = n >> 4, ent = n & 15;
    int tid = threadIdx.x, lane = tid & 63, wid = tid >> 6;
    int l15 = lane & 15;
    int kb = (lane >> 4) * 8;
    int crow = (lane >> 4) * 4;

    // key-padding mask bits for s = lane*8 + j
    unsigned att8 = 0;
    {
        size_t mbase = ((size_t)b * EN + ent) * SL + lane * 8;
        if (flag[0]) {
            const int* p = (const int*)ents;
#pragma unroll
            for (int j = 0; j < 8; ++j)
                if (p[mbase + j]) att8 |= 1u << j;
        } else {
            const unsigned char* p = (const unsigned char*)ents;
#pragma unroll
            for (int j = 0; j < 8; ++j)
                if (p[mbase + j]) att8 |= 1u << j;
        }
    }

    // ---- QK^T: wave w computes all 64 e-rows x s-cols [w*64, w*64+64) ----
    {
        int s0 = wid * 64;
        f32x4 acc[4][4];
#pragma unroll
        for (int i = 0; i < 4; ++i)
#pragma unroll
            for (int j = 0; j < 4; ++j) acc[i][j] = (f32x4)0.f;

        const short* Aq = q_bf + (size_t)l15 * NH + h * DH + kb;
        const short* Bk = K_bf + ((size_t)b * SL + s0 + l15) * NH + h * DH + kb;
        for (int k = 0; k < DH; k += 32) {
            short8 a[4], bb[4];
#pragma unroll
            for (int i = 0; i < 4; ++i) a[i] = *(const short8*)(Aq + (size_t)i * 16 * NH + k);
#pragma unroll
            for (int j = 0; j < 4; ++j) bb[j] = *(const short8*)(Bk + (size_t)j * 16 * NH + k);
#pragma unroll
            for (int i = 0; i < 4; ++i)
#pragma unroll
                for (int j = 0; j < 4; ++j) acc[i][j] = MFMA16(a[i], bb[j], acc[i][j]);
        }

        // store S (bf16) into the swizzled P layout
#pragma unroll
        for (int i = 0; i < 4; ++i)
#pragma unroll
            for (int j = 0; j < 4; ++j) {
                int col = s0 + j * 16 + l15;
                int g = col >> 3, cs = col & 7;
#pragma unroll
                for (int r = 0; r < 4; ++r) {
                    int e = i * 16 + crow + r;
                    Pld[e * SL + ((g ^ (e & 7)) * 8) + cs] = f2b(acc[i][j][r]);
                }
            }
    }
    __syncthreads();

    // ---- softmax in place: wave w owns rows w*8 .. w*8+7 ----
    for (int it = 0; it < 8; ++it) {
        int e = wid * 8 + it;
        short* rowp = &Pld[e * SL + ((lane ^ (e & 7)) * 8)];
        short8 sr = *(const short8*)rowp;
        float v[8];
#pragma unroll
        for (int j = 0; j < 8; ++j) v[j] = (att8 >> j & 1) ? b2f(sr[j]) : -1e9f;
        float m = v[0];
#pragma unroll
        for (int j = 1; j < 8; ++j) m = fmaxf(m, v[j]);
        for (int off = 32; off; off >>= 1) m = fmaxf(m, __shfl_xor(m, off));
        float p[8], sum = 0.f;
#pragma unroll
        for (int j = 0; j < 8; ++j) {
            p[j] = expf(v[j] - m);
            sum += p[j];
        }
        for (int off = 32; off; off >>= 1) sum += __shfl_xor(sum, off);
        float inv = 1.f / sum;
        short8 pv;
#pragma unroll
        for (int j = 0; j < 8; ++j) pv[j] = f2b(p[j] * inv);
        *(short8*)rowp = pv;
    }
    __syncthreads();

    // ---- PV: wave = (ehalf, dquad): rows e0..e0+31, cols n0..n0+63 ----
    int e0 = (wid >> 2) * 32;
    int n0 = (wid & 3) * 64;
    f32x4 acc[2][4];
#pragma unroll
    for (int i = 0; i < 2; ++i)
#pragma unroll
        for (int j = 0; j < 4; ++j) acc[i][j] = (f32x4)0.f;

    const short* Bv = Vt_bf + ((size_t)b * NH + h * DH + n0 + l15) * SL + kb;
    for (int k = 0; k < SL; k += 32) {
        int g = (k + kb) >> 3;
        short8 a[2], bb[4];
#pragma unroll
        for (int i = 0; i < 2; ++i) {
            int e = e0 + i * 16 + l15;
            a[i] = *(const short8*)&Pld[e * SL + ((g ^ (e & 7)) * 8)];
        }
#pragma unroll
        for (int j = 0; j < 4; ++j) bb[j] = *(const short8*)(Bv + (size_t)j * 16 * SL + k);
#pragma unroll
        for (int i = 0; i < 2; ++i)
#pragma unroll
            for (int j = 0; j < 4; ++j) acc[i][j] = MFMA16(a[i], bb[j], acc[i][j]);
    }

#pragma unroll
    for (int i = 0; i < 2; ++i)
#pragma unroll
        for (int j = 0; j < 4; ++j) {
            int col = h * DH + n0 + j * 16 + l15;
#pragma unroll
            for (int r = 0; r < 4; ++r) {
                int row = e0 + i * 16 + crow + r;
                ctx_bf[((size_t)n * NE + row) * NH + col] = f2b(acc[i][j][r]);
            }
        }
}

// ---------------------------------------------------------------------------
// out = ctx_bf @ Wo^T + bo. M=8192, N=512, K=512. 128x128 blocks, 64x64/wave.
__global__ void out_mfma(const short* __restrict__ ctx_bf,
                         const short* __restrict__ Wo_bf,
                         const float* __restrict__ bo,
                         float* __restrict__ out) {
    int mt = blockIdx.x, nt = blockIdx.y;
    int tid = threadIdx.x, lane = tid & 63, wid = tid >> 6;
    int l15 = lane & 15;
    int wm = wid >> 1, wn = wid & 1;
    int m0 = mt * 128 + wm * 64;
    int n0 = nt * 128 + wn * 64;
    int kb = (lane >> 4) * 8;

    f32x4 acc[4][4];
#pragma unroll
    for (int i = 0; i < 4; ++i)
#pragma unroll
        for (int j = 0; j < 4; ++j) acc[i][j] = (f32x4)0.f;

    const short* A = ctx_bf + (size_t)(m0 + l15) * NH + kb;
    const short* B = Wo_bf + (size_t)(n0 + l15) * NH + kb;
    for (int k = 0; k < NH; k += 32) {
        short8 a[4], bb[4];
#pragma unroll
        for (int i = 0; i < 4; ++i) a[i] = *(const short8*)(A + (size_t)i * 16 * NH + k);
#pragma unroll
        for (int j = 0; j < 4; ++j) bb[j] = *(const short8*)(B + (size_t)j * 16 * NH + k);
#pragma unroll
        for (int i = 0; i < 4; ++i)
#pragma unroll
            for (int j = 0; j < 4; ++j) acc[i][j] = MFMA16(a[i], bb[j], acc[i][j]);
    }

    int crow = (lane >> 4) * 4;
#pragma unroll
    for (int i = 0; i < 4; ++i)
#pragma unroll
        for (int j = 0; j < 4; ++j) {
            int col = n0 + j * 16 + l15;
            float bval = bo[col];
#pragma unroll
            for (int r = 0; r < 4; ++r) {
                int row = m0 + i * 16 + crow + r;
                out[(size_t)row * NH + col] = acc[i][j][r] + bval;
            }
        }
}

// ---------------------------------------------------------------------------
extern "C" void kernel_launch(void* const* d_in, const int* in_sizes, int n_in,
                              void* d_out, int out_size, void* d_ws, size_t ws_size,
                              hipStream_t stream) {
    const float* toks = (const float*)d_in[0];
    const void* ents = d_in[1];
    const float* evs = (const float*)d_in[2];
    const float* Wq = (const float*)d_in[6];
    const float* Wk = (const float*)d_in[7];
    const float* Wv = (const float*)d_in[8];
    const float* bq = (const float*)d_in[9];
    const float* bk = (const float*)d_in[10];
    const float* bv = (const float*)d_in[11];
    const float* Wo = (const float*)d_in[12];
    const float* bo = (const float*)d_in[13];

    char* ws = (char*)d_ws;
    short* toks_bf = (short*)(ws + WS_TOKS);
    short* K_bf = (short*)(ws + WS_K);
    short* Vt_bf = (short*)(ws + WS_VT);
    short* ctx_bf = (short*)(ws + WS_CTX);
    short* Wk_bf = (short*)(ws + WS_WK);
    short* Wv_bf = (short*)(ws + WS_WV);
    short* Wo_bf = (short*)(ws + WS_WO);
    short* Wq_bf = (short*)(ws + WS_WQ);
    short* ev_bf = (short*)(ws + WS_EV);
    short* q_bf = (short*)(ws + WS_Q);
    int* flag = (int*)(ws + WS_FLAG);

    prep_kernel<<<CH_TOTAL / 256 + 1, 256, 0, stream>>>(
        toks, Wk, Wv, Wo, Wq, evs, (const unsigned char*)ents,
        toks_bf, Wk_bf, Wv_bf, Wo_bf, Wq_bf, ev_bf, flag);
    proj_kernel<<<260, 256, 0, stream>>>(toks_bf, Wk_bf, Wv_bf, ev_bf, Wq_bf,
                                         bk, bv, bq, K_bf, Vt_bf, q_bf);
    fused_attn<<<dim3(NSLOT, HEADS), 512, 0, stream>>>(q_bf, K_bf, Vt_bf, ents, flag, ctx_bf);
    out_mfma<<<dim3(64, 4), 256, 0, stream>>>(ctx_bf, Wo_bf, bo, (float*)d_out);
}

// Round 7
// 95.271 us; speedup vs baseline: 1.1381x; 1.0648x over previous
//
#include <hip/hip_runtime.h>

// EntityAttention — round 7: scores hoisted per-(b,h), e-split softmax_pv
// (2 blocks/CU), XCD-chunked swizzles everywhere.
// NB=8 SL=512 NH=512 EN=16 NE=64 HEADS=2 DH=256. Selection masks all-True.

#define NB 8
#define SL 512
#define NH 512
#define EN 16
#define NE 64
#define HEADS 2
#define DH 256
#define NSLOT (NB * EN)
#define SCALE 0.0625f

typedef __attribute__((ext_vector_type(8))) short short8;
typedef __attribute__((ext_vector_type(4))) short short4v;
typedef __attribute__((ext_vector_type(4))) float f32x4;

#define MFMA16(a, b, c) __builtin_amdgcn_mfma_f32_16x16x32_bf16(a, b, c, 0, 0, 0)

__device__ __forceinline__ short f2b(float f) {
    unsigned u = __builtin_bit_cast(unsigned, f);
    u += 0x7fffu + ((u >> 16) & 1u);
    return (short)(u >> 16);
}
__device__ __forceinline__ float b2f(short s) {
    return __builtin_bit_cast(float, ((unsigned)(unsigned short)s) << 16);
}
// XCD-chunk swizzle: grid = 8*chunk, hw round-robins XCDs -> logical chunks.
__device__ __forceinline__ int swz8(int hw, int chunk) {
    return (hw & 7) * chunk + (hw >> 3);
}

// ---- ws byte offsets (no aliasing) -----------------------------------------
#define WS_TOKS 0u
#define WS_K (4u << 20)
#define WS_VT (8u << 20)
#define WS_CTX (12u << 20)
#define WS_S (20u << 20)
#define WS_WK (22u << 20)
#define WS_WV (WS_WK + (512u << 10))
#define WS_WO (WS_WV + (512u << 10))
#define WS_WQ (WS_WO + (512u << 10))
#define WS_EV (WS_WQ + (512u << 10))
#define WS_Q (WS_EV + (64u << 10))
#define WS_FLAG (WS_Q + (64u << 10))

// chunk counts (f32x4 units) for prep
#define CH_TOKS (NB * SL * NH / 4) /* 524288 */
#define CH_W (NH * NH / 4)         /* 65536 */
#define CH_EV (NE * NH / 4)        /* 8192 */
#define CH_TOTAL (CH_TOKS + 4 * CH_W + CH_EV) /* 794624 */

// ---------------------------------------------------------------------------
// prep: all fp32->bf16 conversions + bool-encoding detection (last block).
__global__ void prep_kernel(const float* __restrict__ toks, const float* __restrict__ Wk,
                            const float* __restrict__ Wv, const float* __restrict__ Wo,
                            const float* __restrict__ Wq, const float* __restrict__ ev,
                            const unsigned char* __restrict__ ents,
                            short* __restrict__ toks_bf, short* __restrict__ Wk_bf,
                            short* __restrict__ Wv_bf, short* __restrict__ Wo_bf,
                            short* __restrict__ Wq_bf, short* __restrict__ ev_bf,
                            int* __restrict__ flag) {
    __shared__ int red[256];
    int idx = blockIdx.x * 256 + threadIdx.x;
    if (idx < CH_TOTAL) {
        const float* src;
        short* dst;
        int off = idx;
        if (idx < CH_TOKS) { src = toks; dst = toks_bf; }
        else if (idx < CH_TOKS + CH_W) { src = Wk; dst = Wk_bf; off -= CH_TOKS; }
        else if (idx < CH_TOKS + 2 * CH_W) { src = Wv; dst = Wv_bf; off -= CH_TOKS + CH_W; }
        else if (idx < CH_TOKS + 3 * CH_W) { src = Wo; dst = Wo_bf; off -= CH_TOKS + 2 * CH_W; }
        else if (idx < CH_TOKS + 4 * CH_W) { src = Wq; dst = Wq_bf; off -= CH_TOKS + 3 * CH_W; }
        else { src = ev; dst = ev_bf; off -= CH_TOKS + 4 * CH_W; }
        f32x4 v = ((const f32x4*)src)[off];
        short4v o;
#pragma unroll
        for (int j = 0; j < 4; ++j) o[j] = f2b(v[j]);
        ((short4v*)dst)[off] = o;
    }
    if (blockIdx.x == gridDim.x - 1) {
        int tid = threadIdx.x;
        int cnt = 0;
        for (int j = 0; j < 16; ++j) {
            int off = tid * 16 + j;
            if ((off & 3) != 0 && ents[off] != 0) cnt++;
        }
        red[tid] = cnt;
        __syncthreads();
        for (int s = 128; s > 0; s >>= 1) {
            if (tid < s) red[tid] += red[tid + s];
            __syncthreads();
        }
        if (tid == 0) flag[0] = (red[0] == 0) ? 1 : 0;
    }
}

// ---------------------------------------------------------------------------
// proj: hw<256: K/V tiles (XCD-chunked: 32 blocks per batch); hw>=256: q.
// K/V: 128x128 block tile, 4 waves of 64x64 (4x4 frags).
__global__ void proj_kernel(const short* __restrict__ toks_bf,
                            const short* __restrict__ Wk_bf,
                            const short* __restrict__ Wv_bf,
                            const short* __restrict__ ev_bf,
                            const short* __restrict__ Wq_bf,
                            const float* __restrict__ bk, const float* __restrict__ bv,
                            const float* __restrict__ bq,
                            short* __restrict__ K_bf, short* __restrict__ Vt_bf,
                            short* __restrict__ q_bf) {
    int t = blockIdx.x;
    int tid = threadIdx.x, lane = tid & 63, wid = tid >> 6;
    int l15 = lane & 15;
    int kb = (lane >> 4) * 8;
    int crow = (lane >> 4) * 4;

    if (t < 256) {
        int l = swz8(t, 32); // batch-major: b*32 + kind*16 + mt*4 + nt
        int b = l >> 5, kind = (l >> 4) & 1, mt = (l >> 2) & 3, nt = l & 3;
        int m0 = mt * 128 + (wid >> 1) * 64;
        int n0 = nt * 128 + (wid & 1) * 64;
        const short* A = toks_bf + ((size_t)b * SL + m0 + l15) * NH + kb;
        const short* B = (kind ? Wv_bf : Wk_bf) + (size_t)(n0 + l15) * NH + kb;
        const float* bias = kind ? bv : bk;

        f32x4 acc[4][4];
#pragma unroll
        for (int i = 0; i < 4; ++i)
#pragma unroll
            for (int j = 0; j < 4; ++j) acc[i][j] = (f32x4)0.f;

        for (int k = 0; k < NH; k += 32) {
            short8 a[4], bb[4];
#pragma unroll
            for (int i = 0; i < 4; ++i) a[i] = *(const short8*)(A + (size_t)i * 16 * NH + k);
#pragma unroll
            for (int j = 0; j < 4; ++j) bb[j] = *(const short8*)(B + (size_t)j * 16 * NH + k);
#pragma unroll
            for (int i = 0; i < 4; ++i)
#pragma unroll
                for (int j = 0; j < 4; ++j) acc[i][j] = MFMA16(a[i], bb[j], acc[i][j]);
        }

#pragma unroll
        for (int i = 0; i < 4; ++i) {
#pragma unroll
            for (int j = 0; j < 4; ++j) {
                int col = n0 + j * 16 + l15;
                float bval = bias[col];
                int row0 = m0 + i * 16 + crow;
                if (kind == 0) {
#pragma unroll
                    for (int r = 0; r < 4; ++r)
                        K_bf[((size_t)b * SL + row0 + r) * NH + col] = f2b(acc[i][j][r] + bval);
                } else {
                    short4v pack;
#pragma unroll
                    for (int r = 0; r < 4; ++r) pack[r] = f2b(acc[i][j][r] + bval);
                    *(short4v*)(Vt_bf + ((size_t)b * NH + col) * SL + row0) = pack;
                }
            }
        }
    } else {
        // q projection: M=64, N=512 over 4 blocks; wave = 64e x 32cols.
        int tq = t - 256; // 0..3
        int n0 = tq * 128 + wid * 32;
        const short* A = ev_bf + (size_t)l15 * NH + kb;
        const short* B = Wq_bf + (size_t)(n0 + l15) * NH + kb;

        f32x4 acc[4][2];
#pragma unroll
        for (int i = 0; i < 4; ++i)
#pragma unroll
            for (int j = 0; j < 2; ++j) acc[i][j] = (f32x4)0.f;

        for (int k = 0; k < NH; k += 32) {
            short8 a[4], bb[2];
#pragma unroll
            for (int i = 0; i < 4; ++i) a[i] = *(const short8*)(A + (size_t)i * 16 * NH + k);
#pragma unroll
            for (int j = 0; j < 2; ++j) bb[j] = *(const short8*)(B + (size_t)j * 16 * NH + k);
#pragma unroll
            for (int i = 0; i < 4; ++i)
#pragma unroll
                for (int j = 0; j < 2; ++j) acc[i][j] = MFMA16(a[i], bb[j], acc[i][j]);
        }

#pragma unroll
        for (int i = 0; i < 4; ++i)
#pragma unroll
            for (int j = 0; j < 2; ++j) {
                int col = n0 + j * 16 + l15;
                float bval = bq[col];
#pragma unroll
                for (int r = 0; r < 4; ++r)
                    q_bf[(size_t)(i * 16 + crow + r) * NH + col] = f2b((acc[i][j][r] + bval) * SCALE);
            }
    }
}

// ---------------------------------------------------------------------------
// scores: S_bf[b][h][e][s] = q_scaled[e] . K[b][s] (bf16 out). Computed ONCE
// per (b,h) — shared by all 16 entities. grid 64 (XCD-chunked: 8 per batch).
__global__ void scores_mfma(const short* __restrict__ q_bf,
                            const short* __restrict__ K_bf,
                            short* __restrict__ S_bf) {
    int l = swz8(blockIdx.x, 8); // b*8 + h*4 + st
    int b = l >> 3, h = (l >> 2) & 1, st = l & 3;
    int tid = threadIdx.x, lane = tid & 63, wid = tid >> 6;
    int l15 = lane & 15;
    int n0 = st * 128 + wid * 32;
    int kb = (lane >> 4) * 8;

    f32x4 acc[4][2];
#pragma unroll
    for (int i = 0; i < 4; ++i)
#pragma unroll
        for (int j = 0; j < 2; ++j) acc[i][j] = (f32x4)0.f;

    const short* Aq = q_bf + (size_t)l15 * NH + h * DH + kb;
    const short* Bk = K_bf + ((size_t)b * SL + n0 + l15) * NH + h * DH + kb;
    for (int k = 0; k < DH; k += 32) {
        short8 a[4], bb[2];
#pragma unroll
        for (int i = 0; i < 4; ++i) a[i] = *(const short8*)(Aq + (size_t)i * 16 * NH + k);
#pragma unroll
        for (int j = 0; j < 2; ++j) bb[j] = *(const short8*)(Bk + (size_t)j * 16 * NH + k);
#pragma unroll
        for (int i = 0; i < 4; ++i)
#pragma unroll
            for (int j = 0; j < 2; ++j) acc[i][j] = MFMA16(a[i], bb[j], acc[i][j]);
    }

    int crow = (lane >> 4) * 4;
#pragma unroll
    for (int i = 0; i < 4; ++i)
#pragma unroll
        for (int j = 0; j < 2; ++j) {
            int col = n0 + j * 16 + l15;
#pragma unroll
            for (int r = 0; r < 4; ++r) {
                int row = i * 16 + crow + r;
                S_bf[(((size_t)(b * HEADS + h)) * NE + row) * SL + col] = f2b(acc[i][j][r]);
            }
        }
}

// ---------------------------------------------------------------------------
// softmax_pv: block = (slot, head, e-half), 256 thr (4 waves), 32 KB LDS.
// Reads S tile (32x512), masks+softmaxes into swizzled LDS P, then PV.
// grid 1024? no: 128*2*2 = 512 blocks, XCD-chunked 64 per batch.
__global__ void softmax_pv(const short* __restrict__ S_bf,
                           const short* __restrict__ Vt_bf,
                           const void* __restrict__ ents,
                           const int* __restrict__ flag,
                           short* __restrict__ ctx_bf) {
    __shared__ short Pld[32 * SL]; // 32 KB
    int l = swz8(blockIdx.x, 64); // b*64 + ent*4 + h*2 + eh
    int b = l >> 6;
    int r0 = l & 63;
    int ent = r0 >> 2, h = (r0 >> 1) & 1, eh = r0 & 1;
    int n = b * EN + ent;
    int tid = threadIdx.x, lane = tid & 63, wid = tid >> 6;
    int l15 = lane & 15;
    int kb = (lane >> 4) * 8;
    int crow = (lane >> 4) * 4;

    // key-padding mask bits for s = lane*8 + j
    unsigned att8 = 0;
    {
        size_t mbase = ((size_t)b * EN + ent) * SL + lane * 8;
        if (flag[0]) {
            const int* p = (const int*)ents;
#pragma unroll
            for (int j = 0; j < 8; ++j)
                if (p[mbase + j]) att8 |= 1u << j;
        } else {
            const unsigned char* p = (const unsigned char*)ents;
#pragma unroll
            for (int j = 0; j < 8; ++j)
                if (p[mbase + j]) att8 |= 1u << j;
        }
    }

    // ---- load S rows, mask, softmax, store P swizzled. wave w: rows w*8.. ----
    for (int it = 0; it < 8; ++it) {
        int el = wid * 8 + it;          // 0..31 local row
        int e = eh * 32 + el;           // global event
        const short* srow = S_bf + (((size_t)(b * HEADS + h)) * NE + e) * SL + lane * 8;
        short8 sr = *(const short8*)srow;
        float v[8];
#pragma unroll
        for (int j = 0; j < 8; ++j) v[j] = (att8 >> j & 1) ? b2f(sr[j]) : -1e9f;
        float m = v[0];
#pragma unroll
        for (int j = 1; j < 8; ++j) m = fmaxf(m, v[j]);
        for (int off = 32; off; off >>= 1) m = fmaxf(m, __shfl_xor(m, off));
        float p[8], sum = 0.f;
#pragma unroll
        for (int j = 0; j < 8; ++j) {
            p[j] = expf(v[j] - m);
            sum += p[j];
        }
        for (int off = 32; off; off >>= 1) sum += __shfl_xor(sum, off);
        float inv = 1.f / sum;
        short8 pv;
#pragma unroll
        for (int j = 0; j < 8; ++j) pv[j] = f2b(p[j] * inv);
        *(short8*)&Pld[el * SL + ((lane ^ (el & 7)) * 8)] = pv;
    }
    __syncthreads();

    // ---- PV: wave w owns d-strip n0 = w*64 (within head). rows: 32 local. ----
    int n0 = wid * 64;
    f32x4 acc[2][4];
#pragma unroll
    for (int i = 0; i < 2; ++i)
#pragma unroll
        for (int j = 0; j < 4; ++j) acc[i][j] = (f32x4)0.f;

    const short* Bv = Vt_bf + ((size_t)b * NH + h * DH + n0 + l15) * SL + kb;
    for (int k = 0; k < SL; k += 32) {
        int g = (k + kb) >> 3;
        short8 a[2], bb[4];
#pragma unroll
        for (int i = 0; i < 2; ++i) {
            int el = i * 16 + l15;
            a[i] = *(const short8*)&Pld[el * SL + ((g ^ (el & 7)) * 8)];
        }
#pragma unroll
        for (int j = 0; j < 4; ++j) bb[j] = *(const short8*)(Bv + (size_t)j * 16 * SL + k);
#pragma unroll
        for (int i = 0; i < 2; ++i)
#pragma unroll
            for (int j = 0; j < 4; ++j) acc[i][j] = MFMA16(a[i], bb[j], acc[i][j]);
    }

#pragma unroll
    for (int i = 0; i < 2; ++i)
#pragma unroll
        for (int j = 0; j < 4; ++j) {
            int col = h * DH + n0 + j * 16 + l15;
#pragma unroll
            for (int r = 0; r < 4; ++r) {
                int row = eh * 32 + i * 16 + crow + r;
                ctx_bf[((size_t)n * NE + row) * NH + col] = f2b(acc[i][j][r]);
            }
        }
}

// ---------------------------------------------------------------------------
// out = ctx_bf @ Wo^T + bo. M=8192, N=512, K=512. 128x128 blocks, 64x64/wave.
// 1D grid 256, XCD-chunked (32 blocks = 8 m-tiles per XCD).
__global__ void out_mfma(const short* __restrict__ ctx_bf,
                         const short* __restrict__ Wo_bf,
                         const float* __restrict__ bo,
                         float* __restrict__ out) {
    int l = swz8(blockIdx.x, 32); // mt*4 + nt
    int mt = l >> 2, nt = l & 3;
    int tid = threadIdx.x, lane = tid & 63, wid = tid >> 6;
    int l15 = lane & 15;
    int wm = wid >> 1, wn = wid & 1;
    int m0 = mt * 128 + wm * 64;
    int n0 = nt * 128 + wn * 64;
    int kb = (lane >> 4) * 8;

    f32x4 acc[4][4];
#pragma unroll
    for (int i = 0; i < 4; ++i)
#pragma unroll
        for (int j = 0; j < 4; ++j) acc[i][j] = (f32x4)0.f;

    const short* A = ctx_bf + (size_t)(m0 + l15) * NH + kb;
    const short* B = Wo_bf + (size_t)(n0 + l15) * NH + kb;
    for (int k = 0; k < NH; k += 32) {
        short8 a[4], bb[4];
#pragma unroll
        for (int i = 0; i < 4; ++i) a[i] = *(const short8*)(A + (size_t)i * 16 * NH + k);
#pragma unroll
        for (int j = 0; j < 4; ++j) bb[j] = *(const short8*)(B + (size_t)j * 16 * NH + k);
#pragma unroll
        for (int i = 0; i < 4; ++i)
#pragma unroll
            for (int j = 0; j < 4; ++j) acc[i][j] = MFMA16(a[i], bb[j], acc[i][j]);
    }

    int crow = (lane >> 4) * 4;
#pragma unroll
    for (int i = 0; i < 4; ++i)
#pragma unroll
        for (int j = 0; j < 4; ++j) {
            int col = n0 + j * 16 + l15;
            float bval = bo[col];
#pragma unroll
            for (int r = 0; r < 4; ++r) {
                int row = m0 + i * 16 + crow + r;
                out[(size_t)row * NH + col] = acc[i][j][r] + bval;
            }
        }
}

// ---------------------------------------------------------------------------
extern "C" void kernel_launch(void* const* d_in, const int* in_sizes, int n_in,
                              void* d_out, int out_size, void* d_ws, size_t ws_size,
                              hipStream_t stream) {
    const float* toks = (const float*)d_in[0];
    const void* ents = d_in[1];
    const float* evs = (const float*)d_in[2];
    const float* Wq = (const float*)d_in[6];
    const float* Wk = (const float*)d_in[7];
    const float* Wv = (const float*)d_in[8];
    const float* bq = (const float*)d_in[9];
    const float* bk = (const float*)d_in[10];
    const float* bv = (const float*)d_in[11];
    const float* Wo = (const float*)d_in[12];
    const float* bo = (const float*)d_in[13];

    char* ws = (char*)d_ws;
    short* toks_bf = (short*)(ws + WS_TOKS);
    short* K_bf = (short*)(ws + WS_K);
    short* Vt_bf = (short*)(ws + WS_VT);
    short* ctx_bf = (short*)(ws + WS_CTX);
    short* S_bf = (short*)(ws + WS_S);
    short* Wk_bf = (short*)(ws + WS_WK);
    short* Wv_bf = (short*)(ws + WS_WV);
    short* Wo_bf = (short*)(ws + WS_WO);
    short* Wq_bf = (short*)(ws + WS_WQ);
    short* ev_bf = (short*)(ws + WS_EV);
    short* q_bf = (short*)(ws + WS_Q);
    int* flag = (int*)(ws + WS_FLAG);

    prep_kernel<<<CH_TOTAL / 256 + 1, 256, 0, stream>>>(
        toks, Wk, Wv, Wo, Wq, evs, (const unsigned char*)ents,
        toks_bf, Wk_bf, Wv_bf, Wo_bf, Wq_bf, ev_bf, flag);
    proj_kernel<<<260, 256, 0, stream>>>(toks_bf, Wk_bf, Wv_bf, ev_bf, Wq_bf,
                                         bk, bv, bq, K_bf, Vt_bf, q_bf);
    scores_mfma<<<64, 256, 0, stream>>>(q_bf, K_bf, S_bf);
    softmax_pv<<<512, 256, 0, stream>>>(S_bf, Vt_bf, ents, flag, ctx_bf);
    out_mfma<<<256, 256, 0, stream>>>(ctx_bf, Wo_bf, bo, (float*)d_out);
}

// Round 8
// 92.191 us; speedup vs baseline: 1.1761x; 1.0334x over previous
//
#include <hip/hip_runtime.h>

// EntityAttention — round 8: softmax+PV+out-GEMM fused into one kernel
// (removes ctx global round-trip + one launch). prep/proj/scores as R7.
// NB=8 SL=512 NH=512 EN=16 NE=64 HEADS=2 DH=256. Selection masks all-True.

#define NB 8
#define SL 512
#define NH 512
#define EN 16
#define NE 64
#define HEADS 2
#define DH 256
#define NSLOT (NB * EN)
#define SCALE 0.0625f

typedef __attribute__((ext_vector_type(8))) short short8;
typedef __attribute__((ext_vector_type(4))) short short4v;
typedef __attribute__((ext_vector_type(4))) float f32x4;

#define MFMA16(a, b, c) __builtin_amdgcn_mfma_f32_16x16x32_bf16(a, b, c, 0, 0, 0)

__device__ __forceinline__ short f2b(float f) {
    unsigned u = __builtin_bit_cast(unsigned, f);
    u += 0x7fffu + ((u >> 16) & 1u);
    return (short)(u >> 16);
}
__device__ __forceinline__ float b2f(short s) {
    return __builtin_bit_cast(float, ((unsigned)(unsigned short)s) << 16);
}
// XCD-chunk swizzle: grid = 8*chunk, hw round-robins XCDs -> logical chunks.
__device__ __forceinline__ int swz8(int hw, int chunk) {
    return (hw & 7) * chunk + (hw >> 3);
}

// ---- ws byte offsets (no aliasing) -----------------------------------------
#define WS_TOKS 0u
#define WS_K (4u << 20)
#define WS_VT (8u << 20)
#define WS_S (20u << 20)
#define WS_WK (22u << 20)
#define WS_WV (WS_WK + (512u << 10))
#define WS_WO (WS_WV + (512u << 10))
#define WS_WQ (WS_WO + (512u << 10))
#define WS_EV (WS_WQ + (512u << 10))
#define WS_Q (WS_EV + (64u << 10))
#define WS_FLAG (WS_Q + (64u << 10))

// chunk counts (f32x4 units) for prep
#define CH_TOKS (NB * SL * NH / 4) /* 524288 */
#define CH_W (NH * NH / 4)         /* 65536 */
#define CH_EV (NE * NH / 4)        /* 8192 */
#define CH_TOTAL (CH_TOKS + 4 * CH_W + CH_EV) /* 794624 */

// ---------------------------------------------------------------------------
// prep: all fp32->bf16 conversions + bool-encoding detection (last block).
__global__ void prep_kernel(const float* __restrict__ toks, const float* __restrict__ Wk,
                            const float* __restrict__ Wv, const float* __restrict__ Wo,
                            const float* __restrict__ Wq, const float* __restrict__ ev,
                            const unsigned char* __restrict__ ents,
                            short* __restrict__ toks_bf, short* __restrict__ Wk_bf,
                            short* __restrict__ Wv_bf, short* __restrict__ Wo_bf,
                            short* __restrict__ Wq_bf, short* __restrict__ ev_bf,
                            int* __restrict__ flag) {
    __shared__ int red[256];
    int idx = blockIdx.x * 256 + threadIdx.x;
    if (idx < CH_TOTAL) {
        const float* src;
        short* dst;
        int off = idx;
        if (idx < CH_TOKS) { src = toks; dst = toks_bf; }
        else if (idx < CH_TOKS + CH_W) { src = Wk; dst = Wk_bf; off -= CH_TOKS; }
        else if (idx < CH_TOKS + 2 * CH_W) { src = Wv; dst = Wv_bf; off -= CH_TOKS + CH_W; }
        else if (idx < CH_TOKS + 3 * CH_W) { src = Wo; dst = Wo_bf; off -= CH_TOKS + 2 * CH_W; }
        else if (idx < CH_TOKS + 4 * CH_W) { src = Wq; dst = Wq_bf; off -= CH_TOKS + 3 * CH_W; }
        else { src = ev; dst = ev_bf; off -= CH_TOKS + 4 * CH_W; }
        f32x4 v = ((const f32x4*)src)[off];
        short4v o;
#pragma unroll
        for (int j = 0; j < 4; ++j) o[j] = f2b(v[j]);
        ((short4v*)dst)[off] = o;
    }
    if (blockIdx.x == gridDim.x - 1) {
        int tid = threadIdx.x;
        int cnt = 0;
        for (int j = 0; j < 16; ++j) {
            int off = tid * 16 + j;
            if ((off & 3) != 0 && ents[off] != 0) cnt++;
        }
        red[tid] = cnt;
        __syncthreads();
        for (int s = 128; s > 0; s >>= 1) {
            if (tid < s) red[tid] += red[tid + s];
            __syncthreads();
        }
        if (tid == 0) flag[0] = (red[0] == 0) ? 1 : 0;
    }
}

// ---------------------------------------------------------------------------
// proj: hw<256: K/V tiles (XCD-chunked: 32 blocks per batch); hw>=256: q.
// K/V: 128x128 block tile, 4 waves of 64x64 (4x4 frags).
__global__ void proj_kernel(const short* __restrict__ toks_bf,
                            const short* __restrict__ Wk_bf,
                            const short* __restrict__ Wv_bf,
                            const short* __restrict__ ev_bf,
                            const short* __restrict__ Wq_bf,
                            const float* __restrict__ bk, const float* __restrict__ bv,
                            const float* __restrict__ bq,
                            short* __restrict__ K_bf, short* __restrict__ Vt_bf,
                            short* __restrict__ q_bf) {
    int t = blockIdx.x;
    int tid = threadIdx.x, lane = tid & 63, wid = tid >> 6;
    int l15 = lane & 15;
    int kb = (lane >> 4) * 8;
    int crow = (lane >> 4) * 4;

    if (t < 256) {
        int l = swz8(t, 32); // batch-major: b*32 + kind*16 + mt*4 + nt
        int b = l >> 5, kind = (l >> 4) & 1, mt = (l >> 2) & 3, nt = l & 3;
        int m0 = mt * 128 + (wid >> 1) * 64;
        int n0 = nt * 128 + (wid & 1) * 64;
        const short* A = toks_bf + ((size_t)b * SL + m0 + l15) * NH + kb;
        const short* B = (kind ? Wv_bf : Wk_bf) + (size_t)(n0 + l15) * NH + kb;
        const float* bias = kind ? bv : bk;

        f32x4 acc[4][4];
#pragma unroll
        for (int i = 0; i < 4; ++i)
#pragma unroll
            for (int j = 0; j < 4; ++j) acc[i][j] = (f32x4)0.f;

        for (int k = 0; k < NH; k += 32) {
            short8 a[4], bb[4];
#pragma unroll
            for (int i = 0; i < 4; ++i) a[i] = *(const short8*)(A + (size_t)i * 16 * NH + k);
#pragma unroll
            for (int j = 0; j < 4; ++j) bb[j] = *(const short8*)(B + (size_t)j * 16 * NH + k);
#pragma unroll
            for (int i = 0; i < 4; ++i)
#pragma unroll
                for (int j = 0; j < 4; ++j) acc[i][j] = MFMA16(a[i], bb[j], acc[i][j]);
        }

#pragma unroll
        for (int i = 0; i < 4; ++i) {
#pragma unroll
            for (int j = 0; j < 4; ++j) {
                int col = n0 + j * 16 + l15;
                float bval = bias[col];
                int row0 = m0 + i * 16 + crow;
                if (kind == 0) {
#pragma unroll
                    for (int r = 0; r < 4; ++r)
                        K_bf[((size_t)b * SL + row0 + r) * NH + col] = f2b(acc[i][j][r] + bval);
                } else {
                    short4v pack;
#pragma unroll
                    for (int r = 0; r < 4; ++r) pack[r] = f2b(acc[i][j][r] + bval);
                    *(short4v*)(Vt_bf + ((size_t)b * NH + col) * SL + row0) = pack;
                }
            }
        }
    } else {
        // q projection: M=64, N=512 over 4 blocks; wave = 64e x 32cols.
        int tq = t - 256; // 0..3
        int n0 = tq * 128 + wid * 32;
        const short* A = ev_bf + (size_t)l15 * NH + kb;
        const short* B = Wq_bf + (size_t)(n0 + l15) * NH + kb;

        f32x4 acc[4][2];
#pragma unroll
        for (int i = 0; i < 4; ++i)
#pragma unroll
            for (int j = 0; j < 2; ++j) acc[i][j] = (f32x4)0.f;

        for (int k = 0; k < NH; k += 32) {
            short8 a[4], bb[2];
#pragma unroll
            for (int i = 0; i < 4; ++i) a[i] = *(const short8*)(A + (size_t)i * 16 * NH + k);
#pragma unroll
            for (int j = 0; j < 2; ++j) bb[j] = *(const short8*)(B + (size_t)j * 16 * NH + k);
#pragma unroll
            for (int i = 0; i < 4; ++i)
#pragma unroll
                for (int j = 0; j < 2; ++j) acc[i][j] = MFMA16(a[i], bb[j], acc[i][j]);
        }

#pragma unroll
        for (int i = 0; i < 4; ++i)
#pragma unroll
            for (int j = 0; j < 2; ++j) {
                int col = n0 + j * 16 + l15;
                float bval = bq[col];
#pragma unroll
                for (int r = 0; r < 4; ++r)
                    q_bf[(size_t)(i * 16 + crow + r) * NH + col] = f2b((acc[i][j][r] + bval) * SCALE);
            }
    }
}

// ---------------------------------------------------------------------------
// scores: S_bf[b][h][e][s] = q_scaled[e] . K[b][s] (bf16 out). Computed ONCE
// per (b,h). grid 64 (XCD-chunked: 8 per batch).
__global__ void scores_mfma(const short* __restrict__ q_bf,
                            const short* __restrict__ K_bf,
                            short* __restrict__ S_bf) {
    int l = swz8(blockIdx.x, 8); // b*8 + h*4 + st
    int b = l >> 3, h = (l >> 2) & 1, st = l & 3;
    int tid = threadIdx.x, lane = tid & 63, wid = tid >> 6;
    int l15 = lane & 15;
    int n0 = st * 128 + wid * 32;
    int kb = (lane >> 4) * 8;

    f32x4 acc[4][2];
#pragma unroll
    for (int i = 0; i < 4; ++i)
#pragma unroll
        for (int j = 0; j < 2; ++j) acc[i][j] = (f32x4)0.f;

    const short* Aq = q_bf + (size_t)l15 * NH + h * DH + kb;
    const short* Bk = K_bf + ((size_t)b * SL + n0 + l15) * NH + h * DH + kb;
    for (int k = 0; k < DH; k += 32) {
        short8 a[4], bb[2];
#pragma unroll
        for (int i = 0; i < 4; ++i) a[i] = *(const short8*)(Aq + (size_t)i * 16 * NH + k);
#pragma unroll
        for (int j = 0; j < 2; ++j) bb[j] = *(const short8*)(Bk + (size_t)j * 16 * NH + k);
#pragma unroll
        for (int i = 0; i < 4; ++i)
#pragma unroll
            for (int j = 0; j < 2; ++j) acc[i][j] = MFMA16(a[i], bb[j], acc[i][j]);
    }

    int crow = (lane >> 4) * 4;
#pragma unroll
    for (int i = 0; i < 4; ++i)
#pragma unroll
        for (int j = 0; j < 2; ++j) {
            int col = n0 + j * 16 + l15;
#pragma unroll
            for (int r = 0; r < 4; ++r) {
                int row = i * 16 + crow + r;
                S_bf[(((size_t)(b * HEADS + h)) * NE + row) * SL + col] = f2b(acc[i][j][r]);
            }
        }
}

// ---------------------------------------------------------------------------
// attn_out: softmax -> PV -> out-GEMM, fused. Block = (slot n, e-half eh),
// 512 thr (8 waves). LDS: P[2 heads][32 rows][512] bf16 swizzled (64 KB);
// after PV, ctx (bf16, swizzled) reuses the h0 P buffer; out-GEMM reads ctx
// from LDS + Wo from L2 and writes d_out directly.
// Swizzle: element (row, c) at short index row*512 + ((c>>3 ^ (row&7))*8)+(c&7).
__global__ void attn_out(const short* __restrict__ S_bf,
                         const short* __restrict__ Vt_bf,
                         const void* __restrict__ ents,
                         const int* __restrict__ flag,
                         const short* __restrict__ Wo_bf,
                         const float* __restrict__ bo,
                         float* __restrict__ out) {
    __shared__ short Pld[2 * 32 * SL]; // 64 KB
    int l = swz8(blockIdx.x, 32); // b*32 + ent*2 + eh
    int b = l >> 5;
    int ent = (l >> 1) & 15, eh = l & 1;
    int n = b * EN + ent;
    int tid = threadIdx.x, lane = tid & 63, wid = tid >> 6;
    int l15 = lane & 15;
    int kb = (lane >> 4) * 8;
    int crow = (lane >> 4) * 4;

    // key-padding mask bits for s = lane*8 + j
    unsigned att8 = 0;
    {
        size_t mbase = ((size_t)b * EN + ent) * SL + lane * 8;
        if (flag[0]) {
            const int* p = (const int*)ents;
#pragma unroll
            for (int j = 0; j < 8; ++j)
                if (p[mbase + j]) att8 |= 1u << j;
        } else {
            const unsigned char* p = (const unsigned char*)ents;
#pragma unroll
            for (int j = 0; j < 8; ++j)
                if (p[mbase + j]) att8 |= 1u << j;
        }
    }

    // ---- Phase A: softmax. wave w: head h=w>>2, rows el=(w&3)*8..+8 ----
    {
        int h = wid >> 2;
        for (int it = 0; it < 8; ++it) {
            int el = (wid & 3) * 8 + it;       // 0..31 local row
            int e = eh * 32 + el;              // global event
            const short* srow = S_bf + (((size_t)(b * HEADS + h)) * NE + e) * SL + lane * 8;
            short8 sr = *(const short8*)srow;
            float v[8];
#pragma unroll
            for (int j = 0; j < 8; ++j) v[j] = (att8 >> j & 1) ? b2f(sr[j]) : -1e9f;
            float m = v[0];
#pragma unroll
            for (int j = 1; j < 8; ++j) m = fmaxf(m, v[j]);
            for (int off = 32; off; off >>= 1) m = fmaxf(m, __shfl_xor(m, off));
            float p[8], sum = 0.f;
#pragma unroll
            for (int j = 0; j < 8; ++j) {
                p[j] = expf(v[j] - m);
                sum += p[j];
            }
            for (int off = 32; off; off >>= 1) sum += __shfl_xor(sum, off);
            float inv = 1.f / sum;
            short8 pv;
#pragma unroll
            for (int j = 0; j < 8; ++j) pv[j] = f2b(p[j] * inv);
            *(short8*)&Pld[h * (32 * SL) + el * SL + ((lane ^ (el & 7)) * 8)] = pv;
        }
    }
    __syncthreads();

    // ---- Phase B: PV. wave w = (h = w>>2, dq = w&3): rows 32, cols dq*64.. ----
    f32x4 acc[2][4];
    int h = wid >> 2, dq = wid & 3;
    {
#pragma unroll
        for (int i = 0; i < 2; ++i)
#pragma unroll
            for (int j = 0; j < 4; ++j) acc[i][j] = (f32x4)0.f;

        const short* Bv = Vt_bf + ((size_t)b * NH + h * DH + dq * 64 + l15) * SL + kb;
        const short* Ph = &Pld[h * (32 * SL)];
        for (int k = 0; k < SL; k += 32) {
            int g = (k + kb) >> 3;
            short8 a[2], bb[4];
#pragma unroll
            for (int i = 0; i < 2; ++i) {
                int el = i * 16 + l15;
                a[i] = *(const short8*)&Ph[el * SL + ((g ^ (el & 7)) * 8)];
            }
#pragma unroll
            for (int j = 0; j < 4; ++j) bb[j] = *(const short8*)(Bv + (size_t)j * 16 * SL + k);
#pragma unroll
            for (int i = 0; i < 2; ++i)
#pragma unroll
                for (int j = 0; j < 4; ++j) acc[i][j] = MFMA16(a[i], bb[j], acc[i][j]);
        }
    }
    __syncthreads();

    // ---- Phase C: ctx -> LDS (reuse Pld[0..32*SL), h0's P is dead) ----
#pragma unroll
    for (int i = 0; i < 2; ++i)
#pragma unroll
        for (int j = 0; j < 4; ++j) {
            int dg = h * DH + dq * 64 + j * 16 + l15; // 0..511
            int g = dg >> 3, cs = dg & 7;
#pragma unroll
            for (int r = 0; r < 4; ++r) {
                int el = i * 16 + crow + r;
                Pld[el * SL + ((g ^ (el & 7)) * 8) + cs] = f2b(acc[i][j][r]);
            }
        }
    __syncthreads();

    // ---- Phase D: out tile [32 x 512] = ctx @ Wo^T + bo. wave w: cols w*64 ----
    {
        int n0 = wid * 64;
        f32x4 oacc[2][4];
#pragma unroll
        for (int i = 0; i < 2; ++i)
#pragma unroll
            for (int j = 0; j < 4; ++j) oacc[i][j] = (f32x4)0.f;

        const short* Bw = Wo_bf + (size_t)(n0 + l15) * NH + kb;
        for (int k = 0; k < NH; k += 32) {
            int g = (k + kb) >> 3;
            short8 a[2], bb[4];
#pragma unroll
            for (int i = 0; i < 2; ++i) {
                int el = i * 16 + l15;
                a[i] = *(const short8*)&Pld[el * SL + ((g ^ (el & 7)) * 8)];
            }
#pragma unroll
            for (int j = 0; j < 4; ++j) bb[j] = *(const short8*)(Bw + (size_t)j * 16 * NH + k);
#pragma unroll
            for (int i = 0; i < 2; ++i)
#pragma unroll
                for (int j = 0; j < 4; ++j) oacc[i][j] = MFMA16(a[i], bb[j], oacc[i][j]);
        }

        size_t rbase = (size_t)n * NE + eh * 32;
#pragma unroll
        for (int i = 0; i < 2; ++i)
#pragma unroll
            for (int j = 0; j < 4; ++j) {
                int col = n0 + j * 16 + l15;
                float bval = bo[col];
#pragma unroll
                for (int r = 0; r < 4; ++r) {
                    size_t row = rbase + i * 16 + crow + r;
                    out[row * NH + col] = oacc[i][j][r] + bval;
                }
            }
    }
}

// ---------------------------------------------------------------------------
extern "C" void kernel_launch(void* const* d_in, const int* in_sizes, int n_in,
                              void* d_out, int out_size, void* d_ws, size_t ws_size,
                              hipStream_t stream) {
    const float* toks = (const float*)d_in[0];
    const void* ents = d_in[1];
    const float* evs = (const float*)d_in[2];
    const float* Wq = (const float*)d_in[6];
    const float* Wk = (const float*)d_in[7];
    const float* Wv = (const float*)d_in[8];
    const float* bq = (const float*)d_in[9];
    const float* bk = (const float*)d_in[10];
    const float* bv = (const float*)d_in[11];
    const float* Wo = (const float*)d_in[12];
    const float* bo = (const float*)d_in[13];

    char* ws = (char*)d_ws;
    short* toks_bf = (short*)(ws + WS_TOKS);
    short* K_bf = (short*)(ws + WS_K);
    short* Vt_bf = (short*)(ws + WS_VT);
    short* S_bf = (short*)(ws + WS_S);
    short* Wk_bf = (short*)(ws + WS_WK);
    short* Wv_bf = (short*)(ws + WS_WV);
    short* Wo_bf = (short*)(ws + WS_WO);
    short* Wq_bf = (short*)(ws + WS_WQ);
    short* ev_bf = (short*)(ws + WS_EV);
    short* q_bf = (short*)(ws + WS_Q);
    int* flag = (int*)(ws + WS_FLAG);

    prep_kernel<<<CH_TOTAL / 256 + 1, 256, 0, stream>>>(
        toks, Wk, Wv, Wo, Wq, evs, (const unsigned char*)ents,
        toks_bf, Wk_bf, Wv_bf, Wo_bf, Wq_bf, ev_bf, flag);
    proj_kernel<<<260, 256, 0, stream>>>(toks_bf, Wk_bf, Wv_bf, ev_bf, Wq_bf,
                                         bk, bv, bq, K_bf, Vt_bf, q_bf);
    scores_mfma<<<64, 256, 0, stream>>>(q_bf, K_bf, S_bf);
    attn_out<<<256, 512, 0, stream>>>(S_bf, Vt_bf, ents, flag, Wo_bf, bo, (float*)d_out);
}

// Round 9
// 85.461 us; speedup vs baseline: 1.2687x; 1.0787x over previous
//
#include <hip/hip_runtime.h>

// EntityAttention — round 9: explicit 2-deep register pipelining in all GEMM
// k-loops + cross-barrier prefetch + batched no-max softmax.
// NB=8 SL=512 NH=512 EN=16 NE=64 HEADS=2 DH=256. Selection masks all-True.

#define NB 8
#define SL 512
#define NH 512
#define EN 16
#define NE 64
#define HEADS 2
#define DH 256
#define NSLOT (NB * EN)
#define SCALE 0.0625f

typedef __attribute__((ext_vector_type(8))) short short8;
typedef __attribute__((ext_vector_type(4))) short short4v;
typedef __attribute__((ext_vector_type(4))) float f32x4;

#define MFMA16(a, b, c) __builtin_amdgcn_mfma_f32_16x16x32_bf16(a, b, c, 0, 0, 0)

__device__ __forceinline__ short f2b(float f) {
    unsigned u = __builtin_bit_cast(unsigned, f);
    u += 0x7fffu + ((u >> 16) & 1u);
    return (short)(u >> 16);
}
__device__ __forceinline__ float b2f(short s) {
    return __builtin_bit_cast(float, ((unsigned)(unsigned short)s) << 16);
}
// XCD-chunk swizzle: grid = 8*chunk, hw round-robins XCDs -> logical chunks.
__device__ __forceinline__ int swz8(int hw, int chunk) {
    return (hw & 7) * chunk + (hw >> 3);
}

// ---- tiny GEMM helpers (static-index, fully inlined) -----------------------
__device__ __forceinline__ void ldg4(short8 (&d)[4], const short* p, int k, int stride) {
#pragma unroll
    for (int j = 0; j < 4; ++j) d[j] = *(const short8*)(p + (size_t)j * 16 * stride + k);
}
__device__ __forceinline__ void ldg2(short8 (&d)[2], const short* p, int k, int stride) {
#pragma unroll
    for (int j = 0; j < 2; ++j) d[j] = *(const short8*)(p + (size_t)j * 16 * stride + k);
}
__device__ __forceinline__ void ldsw2(short8 (&d)[2], const short* Ph, int k, int kb, int l15) {
    int g = (k + kb) >> 3;
#pragma unroll
    for (int i = 0; i < 2; ++i) {
        int el = i * 16 + l15;
        d[i] = *(const short8*)&Ph[el * SL + ((g ^ (el & 7)) * 8)];
    }
}
__device__ __forceinline__ void mm44(f32x4 (&acc)[4][4], const short8 (&a)[4], const short8 (&bb)[4]) {
#pragma unroll
    for (int i = 0; i < 4; ++i)
#pragma unroll
        for (int j = 0; j < 4; ++j) acc[i][j] = MFMA16(a[i], bb[j], acc[i][j]);
}
__device__ __forceinline__ void mm42(f32x4 (&acc)[4][2], const short8 (&a)[4], const short8 (&bb)[2]) {
#pragma unroll
    for (int i = 0; i < 4; ++i)
#pragma unroll
        for (int j = 0; j < 2; ++j) acc[i][j] = MFMA16(a[i], bb[j], acc[i][j]);
}
__device__ __forceinline__ void mm24(f32x4 (&acc)[2][4], const short8 (&a)[2], const short8 (&bb)[4]) {
#pragma unroll
    for (int i = 0; i < 2; ++i)
#pragma unroll
        for (int j = 0; j < 4; ++j) acc[i][j] = MFMA16(a[i], bb[j], acc[i][j]);
}

// ---- ws byte offsets (no aliasing) -----------------------------------------
#define WS_TOKS 0u
#define WS_K (4u << 20)
#define WS_VT (8u << 20)
#define WS_S (20u << 20)
#define WS_WK (22u << 20)
#define WS_WV (WS_WK + (512u << 10))
#define WS_WO (WS_WV + (512u << 10))
#define WS_WQ (WS_WO + (512u << 10))
#define WS_EV (WS_WQ + (512u << 10))
#define WS_Q (WS_EV + (64u << 10))
#define WS_FLAG (WS_Q + (64u << 10))

// chunk counts (f32x4 units) for prep
#define CH_TOKS (NB * SL * NH / 4) /* 524288 */
#define CH_W (NH * NH / 4)         /* 65536 */
#define CH_EV (NE * NH / 4)        /* 8192 */
#define CH_TOTAL (CH_TOKS + 4 * CH_W + CH_EV) /* 794624 */

// ---------------------------------------------------------------------------
// prep: all fp32->bf16 conversions + bool-encoding detection (last block).
__global__ void prep_kernel(const float* __restrict__ toks, const float* __restrict__ Wk,
                            const float* __restrict__ Wv, const float* __restrict__ Wo,
                            const float* __restrict__ Wq, const float* __restrict__ ev,
                            const unsigned char* __restrict__ ents,
                            short* __restrict__ toks_bf, short* __restrict__ Wk_bf,
                            short* __restrict__ Wv_bf, short* __restrict__ Wo_bf,
                            short* __restrict__ Wq_bf, short* __restrict__ ev_bf,
                            int* __restrict__ flag) {
    __shared__ int red[256];
    int idx = blockIdx.x * 256 + threadIdx.x;
    if (idx < CH_TOTAL) {
        const float* src;
        short* dst;
        int off = idx;
        if (idx < CH_TOKS) { src = toks; dst = toks_bf; }
        else if (idx < CH_TOKS + CH_W) { src = Wk; dst = Wk_bf; off -= CH_TOKS; }
        else if (idx < CH_TOKS + 2 * CH_W) { src = Wv; dst = Wv_bf; off -= CH_TOKS + CH_W; }
        else if (idx < CH_TOKS + 3 * CH_W) { src = Wo; dst = Wo_bf; off -= CH_TOKS + 2 * CH_W; }
        else if (idx < CH_TOKS + 4 * CH_W) { src = Wq; dst = Wq_bf; off -= CH_TOKS + 3 * CH_W; }
        else { src = ev; dst = ev_bf; off -= CH_TOKS + 4 * CH_W; }
        f32x4 v = ((const f32x4*)src)[off];
        short4v o;
#pragma unroll
        for (int j = 0; j < 4; ++j) o[j] = f2b(v[j]);
        ((short4v*)dst)[off] = o;
    }
    if (blockIdx.x == gridDim.x - 1) {
        int tid = threadIdx.x;
        int cnt = 0;
        for (int j = 0; j < 16; ++j) {
            int off = tid * 16 + j;
            if ((off & 3) != 0 && ents[off] != 0) cnt++;
        }
        red[tid] = cnt;
        __syncthreads();
        for (int s = 128; s > 0; s >>= 1) {
            if (tid < s) red[tid] += red[tid + s];
            __syncthreads();
        }
        if (tid == 0) flag[0] = (red[0] == 0) ? 1 : 0;
    }
}

// ---------------------------------------------------------------------------
// proj: hw<256: K/V tiles (XCD-chunked); hw>=256: q. K/V: 128x128 block tile,
// 4 waves of 64x64 (4x4 frags), 2-deep pipelined k-loop.
__global__ void proj_kernel(const short* __restrict__ toks_bf,
                            const short* __restrict__ Wk_bf,
                            const short* __restrict__ Wv_bf,
                            const short* __restrict__ ev_bf,
                            const short* __restrict__ Wq_bf,
                            const float* __restrict__ bk, const float* __restrict__ bv,
                            const float* __restrict__ bq,
                            short* __restrict__ K_bf, short* __restrict__ Vt_bf,
                            short* __restrict__ q_bf) {
    int t = blockIdx.x;
    int tid = threadIdx.x, lane = tid & 63, wid = tid >> 6;
    int l15 = lane & 15;
    int kb = (lane >> 4) * 8;
    int crow = (lane >> 4) * 4;

    if (t < 256) {
        int l = swz8(t, 32); // batch-major: b*32 + kind*16 + mt*4 + nt
        int b = l >> 5, kind = (l >> 4) & 1, mt = (l >> 2) & 3, nt = l & 3;
        int m0 = mt * 128 + (wid >> 1) * 64;
        int n0 = nt * 128 + (wid & 1) * 64;
        const short* A = toks_bf + ((size_t)b * SL + m0 + l15) * NH + kb;
        const short* B = (kind ? Wv_bf : Wk_bf) + (size_t)(n0 + l15) * NH + kb;
        const float* bias = kind ? bv : bk;

        f32x4 acc[4][4];
#pragma unroll
        for (int i = 0; i < 4; ++i)
#pragma unroll
            for (int j = 0; j < 4; ++j) acc[i][j] = (f32x4)0.f;

        short8 a0[4], b0[4], a1[4], b1[4];
        ldg4(a0, A, 0, NH);
        ldg4(b0, B, 0, NH);
#pragma unroll
        for (int p = 0; p < 8; ++p) {
            int k1 = p * 64 + 32;
            ldg4(a1, A, k1, NH);
            ldg4(b1, B, k1, NH);
            mm44(acc, a0, b0);
            if (p < 7) {
                ldg4(a0, A, k1 + 32, NH);
                ldg4(b0, B, k1 + 32, NH);
            }
            mm44(acc, a1, b1);
        }

#pragma unroll
        for (int i = 0; i < 4; ++i) {
#pragma unroll
            for (int j = 0; j < 4; ++j) {
                int col = n0 + j * 16 + l15;
                float bval = bias[col];
                int row0 = m0 + i * 16 + crow;
                if (kind == 0) {
#pragma unroll
                    for (int r = 0; r < 4; ++r)
                        K_bf[((size_t)b * SL + row0 + r) * NH + col] = f2b(acc[i][j][r] + bval);
                } else {
                    short4v pack;
#pragma unroll
                    for (int r = 0; r < 4; ++r) pack[r] = f2b(acc[i][j][r] + bval);
                    *(short4v*)(Vt_bf + ((size_t)b * NH + col) * SL + row0) = pack;
                }
            }
        }
    } else {
        // q projection: M=64, N=512 over 4 blocks; wave = 64e x 32cols.
        int tq = t - 256; // 0..3
        int n0 = tq * 128 + wid * 32;
        const short* A = ev_bf + (size_t)l15 * NH + kb;
        const short* B = Wq_bf + (size_t)(n0 + l15) * NH + kb;

        f32x4 acc[4][2];
#pragma unroll
        for (int i = 0; i < 4; ++i)
#pragma unroll
            for (int j = 0; j < 2; ++j) acc[i][j] = (f32x4)0.f;

        for (int k = 0; k < NH; k += 32) {
            short8 a[4], bb[2];
#pragma unroll
            for (int i = 0; i < 4; ++i) a[i] = *(const short8*)(A + (size_t)i * 16 * NH + k);
#pragma unroll
            for (int j = 0; j < 2; ++j) bb[j] = *(const short8*)(B + (size_t)j * 16 * NH + k);
            mm42(acc, a, bb);
        }

#pragma unroll
        for (int i = 0; i < 4; ++i)
#pragma unroll
            for (int j = 0; j < 2; ++j) {
                int col = n0 + j * 16 + l15;
                float bval = bq[col];
#pragma unroll
                for (int r = 0; r < 4; ++r)
                    q_bf[(size_t)(i * 16 + crow + r) * NH + col] = f2b((acc[i][j][r] + bval) * SCALE);
            }
    }
}

// ---------------------------------------------------------------------------
// scores: S_bf[b][h][e][s] = q_scaled[e] . K[b][s] (bf16 out). grid 64.
// 2-deep pipelined k-loop (DH=256 -> 8 iters -> 4 pairs).
__global__ void scores_mfma(const short* __restrict__ q_bf,
                            const short* __restrict__ K_bf,
                            short* __restrict__ S_bf) {
    int l = swz8(blockIdx.x, 8); // b*8 + h*4 + st
    int b = l >> 3, h = (l >> 2) & 1, st = l & 3;
    int tid = threadIdx.x, lane = tid & 63, wid = tid >> 6;
    int l15 = lane & 15;
    int n0 = st * 128 + wid * 32;
    int kb = (lane >> 4) * 8;

    f32x4 acc[4][2];
#pragma unroll
    for (int i = 0; i < 4; ++i)
#pragma unroll
        for (int j = 0; j < 2; ++j) acc[i][j] = (f32x4)0.f;

    const short* Aq = q_bf + (size_t)l15 * NH + h * DH + kb;
    const short* Bk = K_bf + ((size_t)b * SL + n0 + l15) * NH + h * DH + kb;

    short8 a0[4], a1[4];
    short8 b0[2], b1[2];
    ldg4(a0, Aq, 0, NH);
    ldg2(b0, Bk, 0, NH);
#pragma unroll
    for (int p = 0; p < 4; ++p) {
        int k1 = p * 64 + 32;
        ldg4(a1, Aq, k1, NH);
        ldg2(b1, Bk, k1, NH);
        mm42(acc, a0, b0);
        if (p < 3) {
            ldg4(a0, Aq, k1 + 32, NH);
            ldg2(b0, Bk, k1 + 32, NH);
        }
        mm42(acc, a1, b1);
    }

    int crow = (lane >> 4) * 4;
#pragma unroll
    for (int i = 0; i < 4; ++i)
#pragma unroll
        for (int j = 0; j < 2; ++j) {
            int col = n0 + j * 16 + l15;
#pragma unroll
            for (int r = 0; r < 4; ++r) {
                int row = i * 16 + crow + r;
                S_bf[(((size_t)(b * HEADS + h)) * NE + row) * SL + col] = f2b(acc[i][j][r]);
            }
        }
}

// ---------------------------------------------------------------------------
// attn_out: softmax -> PV -> out-GEMM, fused. Block = (slot n, e-half eh),
// 512 thr (8 waves). Softmax is no-max (shift-invariant; masked -> exp->0),
// batched 8 rows with interleaved butterflies. GEMM phases 2-deep pipelined;
// V iter-0 prefetched before softmax, Wo iter-0 before the ctx barrier.
__global__ void attn_out(const short* __restrict__ S_bf,
                         const short* __restrict__ Vt_bf,
                         const void* __restrict__ ents,
                         const int* __restrict__ flag,
                         const short* __restrict__ Wo_bf,
                         const float* __restrict__ bo,
                         float* __restrict__ out) {
    __shared__ short Pld[2 * 32 * SL]; // 64 KB
    int l = swz8(blockIdx.x, 32); // b*32 + ent*2 + eh
    int b = l >> 5;
    int ent = (l >> 1) & 15, eh = l & 1;
    int n = b * EN + ent;
    int tid = threadIdx.x, lane = tid & 63, wid = tid >> 6;
    int l15 = lane & 15;
    int kb = (lane >> 4) * 8;
    int crow = (lane >> 4) * 4;
    int h = wid >> 2, dq = wid & 3;

    // key-padding mask bits for s = lane*8 + j
    unsigned att8 = 0;
    {
        size_t mbase = ((size_t)b * EN + ent) * SL + lane * 8;
        if (flag[0]) {
            const int* p = (const int*)ents;
#pragma unroll
            for (int j = 0; j < 8; ++j)
                if (p[mbase + j]) att8 |= 1u << j;
        } else {
            const unsigned char* p = (const unsigned char*)ents;
#pragma unroll
            for (int j = 0; j < 8; ++j)
                if (p[mbase + j]) att8 |= 1u << j;
        }
    }

    // ---- early prefetch: PV iter-0 V loads (complete by the barrier) ----
    const short* Bv = Vt_bf + ((size_t)b * NH + h * DH + dq * 64 + l15) * SL + kb;
    short8 bvA[4], bvB[4];
    ldg4(bvA, Bv, 0, SL);

    // ---- Phase A: softmax (no max pass). wave w: head h, rows (w&3)*8.. ----
    {
        const short* Sbase =
            S_bf + (((size_t)(b * HEADS + h)) * NE + eh * 32 + (wid & 3) * 8) * SL + lane * 8;
        short8 sr[8];
#pragma unroll
        for (int it = 0; it < 8; ++it) sr[it] = *(const short8*)(Sbase + (size_t)it * SL);

        float pall[8][8];
        float sums[8];
#pragma unroll
        for (int it = 0; it < 8; ++it) {
            float s = 0.f;
#pragma unroll
            for (int j = 0; j < 8; ++j) {
                float v = (att8 >> j & 1) ? b2f(sr[it][j]) : -1e9f;
                float e = __expf(v);
                pall[it][j] = e;
                s += e;
            }
            sums[it] = s;
        }
        // interleaved butterflies: 8 independent chains per step
#pragma unroll
        for (int off = 32; off; off >>= 1)
#pragma unroll
            for (int it = 0; it < 8; ++it) sums[it] += __shfl_xor(sums[it], off);
#pragma unroll
        for (int it = 0; it < 8; ++it) {
            float iv = 1.f / sums[it];
            short8 pv;
#pragma unroll
            for (int j = 0; j < 8; ++j) pv[j] = f2b(pall[it][j] * iv);
            int el = (wid & 3) * 8 + it;
            *(short8*)&Pld[h * (32 * SL) + el * SL + ((lane ^ (el & 7)) * 8)] = pv;
        }
    }
    __syncthreads();

    // ---- Phase B: PV, 2-deep pipelined. wave (h, dq): 32 rows x 64 cols ----
    f32x4 acc[2][4];
#pragma unroll
    for (int i = 0; i < 2; ++i)
#pragma unroll
        for (int j = 0; j < 4; ++j) acc[i][j] = (f32x4)0.f;
    {
        const short* Ph = &Pld[h * (32 * SL)];
        short8 paA[2], paB[2];
        ldsw2(paA, Ph, 0, kb, l15);
#pragma unroll
        for (int p = 0; p < 8; ++p) {
            int k1 = p * 64 + 32;
            ldg4(bvB, Bv, k1, SL);
            ldsw2(paB, Ph, k1, kb, l15);
            mm24(acc, paA, bvA);
            if (p < 7) {
                ldg4(bvA, Bv, k1 + 32, SL);
                ldsw2(paA, Ph, k1 + 32, kb, l15);
            }
            mm24(acc, paB, bvB);
        }
    }
    __syncthreads();

    // ---- early prefetch: out-GEMM iter-0 Wo loads ----
    const short* Bw = Wo_bf + (size_t)(wid * 64 + l15) * NH + kb;
    short8 bwA[4], bwB[4];
    ldg4(bwA, Bw, 0, NH);

    // ---- Phase C: ctx -> LDS (reuse lower 32 KB; h0's P is dead) ----
#pragma unroll
    for (int i = 0; i < 2; ++i)
#pragma unroll
        for (int j = 0; j < 4; ++j) {
            int dg = h * DH + dq * 64 + j * 16 + l15; // 0..511
            int g = dg >> 3, cs = dg & 7;
#pragma unroll
            for (int r = 0; r < 4; ++r) {
                int el = i * 16 + crow + r;
                Pld[el * SL + ((g ^ (el & 7)) * 8) + cs] = f2b(acc[i][j][r]);
            }
        }
    __syncthreads();

    // ---- Phase D: out tile [32 x 512] = ctx @ Wo^T + bo, 2-deep pipelined ----
    {
        int n0 = wid * 64;
        f32x4 oacc[2][4];
#pragma unroll
        for (int i = 0; i < 2; ++i)
#pragma unroll
            for (int j = 0; j < 4; ++j) oacc[i][j] = (f32x4)0.f;

        short8 caA[2], caB[2];
        ldsw2(caA, Pld, 0, kb, l15);
#pragma unroll
        for (int p = 0; p < 8; ++p) {
            int k1 = p * 64 + 32;
            ldg4(bwB, Bw, k1, NH);
            ldsw2(caB, Pld, k1, kb, l15);
            mm24(oacc, caA, bwA);
            if (p < 7) {
                ldg4(bwA, Bw, k1 + 32, NH);
                ldsw2(caA, Pld, k1 + 32, kb, l15);
            }
            mm24(oacc, caB, bwB);
        }

        size_t rbase = (size_t)n * NE + eh * 32;
#pragma unroll
        for (int i = 0; i < 2; ++i)
#pragma unroll
            for (int j = 0; j < 4; ++j) {
                int col = n0 + j * 16 + l15;
                float bval = bo[col];
#pragma unroll
                for (int r = 0; r < 4; ++r) {
                    size_t row = rbase + i * 16 + crow + r;
                    out[row * NH + col] = oacc[i][j][r] + bval;
                }
            }
    }
}

// ---------------------------------------------------------------------------
extern "C" void kernel_launch(void* const* d_in, const int* in_sizes, int n_in,
                              void* d_out, int out_size, void* d_ws, size_t ws_size,
                              hipStream_t stream) {
    const float* toks = (const float*)d_in[0];
    const void* ents = d_in[1];
    const float* evs = (const float*)d_in[2];
    const float* Wq = (const float*)d_in[6];
    const float* Wk = (const float*)d_in[7];
    const float* Wv = (const float*)d_in[8];
    const float* bq = (const float*)d_in[9];
    const float* bk = (const float*)d_in[10];
    const float* bv = (const float*)d_in[11];
    const float* Wo = (const float*)d_in[12];
    const float* bo = (const float*)d_in[13];

    char* ws = (char*)d_ws;
    short* toks_bf = (short*)(ws + WS_TOKS);
    short* K_bf = (short*)(ws + WS_K);
    short* Vt_bf = (short*)(ws + WS_VT);
    short* S_bf = (short*)(ws + WS_S);
    short* Wk_bf = (short*)(ws + WS_WK);
    short* Wv_bf = (short*)(ws + WS_WV);
    short* Wo_bf = (short*)(ws + WS_WO);
    short* Wq_bf = (short*)(ws + WS_WQ);
    short* ev_bf = (short*)(ws + WS_EV);
    short* q_bf = (short*)(ws + WS_Q);
    int* flag = (int*)(ws + WS_FLAG);

    prep_kernel<<<CH_TOTAL / 256 + 1, 256, 0, stream>>>(
        toks, Wk, Wv, Wo, Wq, evs, (const unsigned char*)ents,
        toks_bf, Wk_bf, Wv_bf, Wo_bf, Wq_bf, ev_bf, flag);
    proj_kernel<<<260, 256, 0, stream>>>(toks_bf, Wk_bf, Wv_bf, ev_bf, Wq_bf,
                                         bk, bv, bq, K_bf, Vt_bf, q_bf);
    scores_mfma<<<64, 256, 0, stream>>>(q_bf, K_bf, S_bf);
    attn_out<<<256, 512, 0, stream>>>(S_bf, Vt_bf, ents, flag, Wo_bf, bo, (float*)d_out);
}

// Round 10
// 85.203 us; speedup vs baseline: 1.2726x; 1.0030x over previous
//
#include <hip/hip_runtime.h>

// EntityAttention — round 10: R9 + __launch_bounds__(…,2) so the register
// allocator (default: 8 waves/SIMD, VGPR<=64) stops serializing the explicit
// 2-deep pipelines; sched_barrier pins cross-phase prefetches.
// NB=8 SL=512 NH=512 EN=16 NE=64 HEADS=2 DH=256. Selection masks all-True.

#define NB 8
#define SL 512
#define NH 512
#define EN 16
#define NE 64
#define HEADS 2
#define DH 256
#define NSLOT (NB * EN)
#define SCALE 0.0625f

typedef __attribute__((ext_vector_type(8))) short short8;
typedef __attribute__((ext_vector_type(4))) short short4v;
typedef __attribute__((ext_vector_type(4))) float f32x4;

#define MFMA16(a, b, c) __builtin_amdgcn_mfma_f32_16x16x32_bf16(a, b, c, 0, 0, 0)

__device__ __forceinline__ short f2b(float f) {
    unsigned u = __builtin_bit_cast(unsigned, f);
    u += 0x7fffu + ((u >> 16) & 1u);
    return (short)(u >> 16);
}
__device__ __forceinline__ float b2f(short s) {
    return __builtin_bit_cast(float, ((unsigned)(unsigned short)s) << 16);
}
// XCD-chunk swizzle: grid = 8*chunk, hw round-robins XCDs -> logical chunks.
__device__ __forceinline__ int swz8(int hw, int chunk) {
    return (hw & 7) * chunk + (hw >> 3);
}

// ---- tiny GEMM helpers (static-index, fully inlined) -----------------------
__device__ __forceinline__ void ldg4(short8 (&d)[4], const short* p, int k, int stride) {
#pragma unroll
    for (int j = 0; j < 4; ++j) d[j] = *(const short8*)(p + (size_t)j * 16 * stride + k);
}
__device__ __forceinline__ void ldg2(short8 (&d)[2], const short* p, int k, int stride) {
#pragma unroll
    for (int j = 0; j < 2; ++j) d[j] = *(const short8*)(p + (size_t)j * 16 * stride + k);
}
__device__ __forceinline__ void ldsw2(short8 (&d)[2], const short* Ph, int k, int kb, int l15) {
    int g = (k + kb) >> 3;
#pragma unroll
    for (int i = 0; i < 2; ++i) {
        int el = i * 16 + l15;
        d[i] = *(const short8*)&Ph[el * SL + ((g ^ (el & 7)) * 8)];
    }
}
__device__ __forceinline__ void mm44(f32x4 (&acc)[4][4], const short8 (&a)[4], const short8 (&bb)[4]) {
#pragma unroll
    for (int i = 0; i < 4; ++i)
#pragma unroll
        for (int j = 0; j < 4; ++j) acc[i][j] = MFMA16(a[i], bb[j], acc[i][j]);
}
__device__ __forceinline__ void mm42(f32x4 (&acc)[4][2], const short8 (&a)[4], const short8 (&bb)[2]) {
#pragma unroll
    for (int i = 0; i < 4; ++i)
#pragma unroll
        for (int j = 0; j < 2; ++j) acc[i][j] = MFMA16(a[i], bb[j], acc[i][j]);
}
__device__ __forceinline__ void mm24(f32x4 (&acc)[2][4], const short8 (&a)[2], const short8 (&bb)[4]) {
#pragma unroll
    for (int i = 0; i < 2; ++i)
#pragma unroll
        for (int j = 0; j < 4; ++j) acc[i][j] = MFMA16(a[i], bb[j], acc[i][j]);
}

// ---- ws byte offsets (no aliasing) -----------------------------------------
#define WS_TOKS 0u
#define WS_K (4u << 20)
#define WS_VT (8u << 20)
#define WS_S (20u << 20)
#define WS_WK (22u << 20)
#define WS_WV (WS_WK + (512u << 10))
#define WS_WO (WS_WV + (512u << 10))
#define WS_WQ (WS_WO + (512u << 10))
#define WS_EV (WS_WQ + (512u << 10))
#define WS_Q (WS_EV + (64u << 10))
#define WS_FLAG (WS_Q + (64u << 10))

// chunk counts (f32x4 units) for prep
#define CH_TOKS (NB * SL * NH / 4) /* 524288 */
#define CH_W (NH * NH / 4)         /* 65536 */
#define CH_EV (NE * NH / 4)        /* 8192 */
#define CH_TOTAL (CH_TOKS + 4 * CH_W + CH_EV) /* 794624 */

// ---------------------------------------------------------------------------
// prep: all fp32->bf16 conversions + bool-encoding detection (last block).
__global__ void prep_kernel(const float* __restrict__ toks, const float* __restrict__ Wk,
                            const float* __restrict__ Wv, const float* __restrict__ Wo,
                            const float* __restrict__ Wq, const float* __restrict__ ev,
                            const unsigned char* __restrict__ ents,
                            short* __restrict__ toks_bf, short* __restrict__ Wk_bf,
                            short* __restrict__ Wv_bf, short* __restrict__ Wo_bf,
                            short* __restrict__ Wq_bf, short* __restrict__ ev_bf,
                            int* __restrict__ flag) {
    __shared__ int red[256];
    int idx = blockIdx.x * 256 + threadIdx.x;
    if (idx < CH_TOTAL) {
        const float* src;
        short* dst;
        int off = idx;
        if (idx < CH_TOKS) { src = toks; dst = toks_bf; }
        else if (idx < CH_TOKS + CH_W) { src = Wk; dst = Wk_bf; off -= CH_TOKS; }
        else if (idx < CH_TOKS + 2 * CH_W) { src = Wv; dst = Wv_bf; off -= CH_TOKS + CH_W; }
        else if (idx < CH_TOKS + 3 * CH_W) { src = Wo; dst = Wo_bf; off -= CH_TOKS + 2 * CH_W; }
        else if (idx < CH_TOKS + 4 * CH_W) { src = Wq; dst = Wq_bf; off -= CH_TOKS + 3 * CH_W; }
        else { src = ev; dst = ev_bf; off -= CH_TOKS + 4 * CH_W; }
        f32x4 v = ((const f32x4*)src)[off];
        short4v o;
#pragma unroll
        for (int j = 0; j < 4; ++j) o[j] = f2b(v[j]);
        ((short4v*)dst)[off] = o;
    }
    if (blockIdx.x == gridDim.x - 1) {
        int tid = threadIdx.x;
        int cnt = 0;
        for (int j = 0; j < 16; ++j) {
            int off = tid * 16 + j;
            if ((off & 3) != 0 && ents[off] != 0) cnt++;
        }
        red[tid] = cnt;
        __syncthreads();
        for (int s = 128; s > 0; s >>= 1) {
            if (tid < s) red[tid] += red[tid + s];
            __syncthreads();
        }
        if (tid == 0) flag[0] = (red[0] == 0) ? 1 : 0;
    }
}

// ---------------------------------------------------------------------------
// proj: hw<256: K/V tiles (XCD-chunked); hw>=256: q. K/V: 128x128 block tile,
// 4 waves of 64x64 (4x4 frags), 2-deep pipelined k-loop.
__global__ void __launch_bounds__(256, 2)
proj_kernel(const short* __restrict__ toks_bf,
            const short* __restrict__ Wk_bf,
            const short* __restrict__ Wv_bf,
            const short* __restrict__ ev_bf,
            const short* __restrict__ Wq_bf,
            const float* __restrict__ bk, const float* __restrict__ bv,
            const float* __restrict__ bq,
            short* __restrict__ K_bf, short* __restrict__ Vt_bf,
            short* __restrict__ q_bf) {
    int t = blockIdx.x;
    int tid = threadIdx.x, lane = tid & 63, wid = tid >> 6;
    int l15 = lane & 15;
    int kb = (lane >> 4) * 8;
    int crow = (lane >> 4) * 4;

    if (t < 256) {
        int l = swz8(t, 32); // batch-major: b*32 + kind*16 + mt*4 + nt
        int b = l >> 5, kind = (l >> 4) & 1, mt = (l >> 2) & 3, nt = l & 3;
        int m0 = mt * 128 + (wid >> 1) * 64;
        int n0 = nt * 128 + (wid & 1) * 64;
        const short* A = toks_bf + ((size_t)b * SL + m0 + l15) * NH + kb;
        const short* B = (kind ? Wv_bf : Wk_bf) + (size_t)(n0 + l15) * NH + kb;
        const float* bias = kind ? bv : bk;

        f32x4 acc[4][4];
#pragma unroll
        for (int i = 0; i < 4; ++i)
#pragma unroll
            for (int j = 0; j < 4; ++j) acc[i][j] = (f32x4)0.f;

        short8 a0[4], b0[4], a1[4], b1[4];
        ldg4(a0, A, 0, NH);
        ldg4(b0, B, 0, NH);
#pragma unroll
        for (int p = 0; p < 8; ++p) {
            int k1 = p * 64 + 32;
            ldg4(a1, A, k1, NH);
            ldg4(b1, B, k1, NH);
            mm44(acc, a0, b0);
            if (p < 7) {
                ldg4(a0, A, k1 + 32, NH);
                ldg4(b0, B, k1 + 32, NH);
            }
            mm44(acc, a1, b1);
        }

#pragma unroll
        for (int i = 0; i < 4; ++i) {
#pragma unroll
            for (int j = 0; j < 4; ++j) {
                int col = n0 + j * 16 + l15;
                float bval = bias[col];
                int row0 = m0 + i * 16 + crow;
                if (kind == 0) {
#pragma unroll
                    for (int r = 0; r < 4; ++r)
                        K_bf[((size_t)b * SL + row0 + r) * NH + col] = f2b(acc[i][j][r] + bval);
                } else {
                    short4v pack;
#pragma unroll
                    for (int r = 0; r < 4; ++r) pack[r] = f2b(acc[i][j][r] + bval);
                    *(short4v*)(Vt_bf + ((size_t)b * NH + col) * SL + row0) = pack;
                }
            }
        }
    } else {
        // q projection: M=64, N=512 over 4 blocks; wave = 64e x 32cols.
        int tq = t - 256; // 0..3
        int n0 = tq * 128 + wid * 32;
        const short* A = ev_bf + (size_t)l15 * NH + kb;
        const short* B = Wq_bf + (size_t)(n0 + l15) * NH + kb;

        f32x4 acc[4][2];
#pragma unroll
        for (int i = 0; i < 4; ++i)
#pragma unroll
            for (int j = 0; j < 2; ++j) acc[i][j] = (f32x4)0.f;

        for (int k = 0; k < NH; k += 32) {
            short8 a[4], bb[2];
#pragma unroll
            for (int i = 0; i < 4; ++i) a[i] = *(const short8*)(A + (size_t)i * 16 * NH + k);
#pragma unroll
            for (int j = 0; j < 2; ++j) bb[j] = *(const short8*)(B + (size_t)j * 16 * NH + k);
            mm42(acc, a, bb);
        }

#pragma unroll
        for (int i = 0; i < 4; ++i)
#pragma unroll
            for (int j = 0; j < 2; ++j) {
                int col = n0 + j * 16 + l15;
                float bval = bq[col];
#pragma unroll
                for (int r = 0; r < 4; ++r)
                    q_bf[(size_t)(i * 16 + crow + r) * NH + col] = f2b((acc[i][j][r] + bval) * SCALE);
            }
    }
}

// ---------------------------------------------------------------------------
// scores: S_bf[b][h][e][s] = q_scaled[e] . K[b][s] (bf16 out). grid 64.
// 2-deep pipelined k-loop (DH=256 -> 8 iters -> 4 pairs).
__global__ void __launch_bounds__(256, 2)
scores_mfma(const short* __restrict__ q_bf,
            const short* __restrict__ K_bf,
            short* __restrict__ S_bf) {
    int l = swz8(blockIdx.x, 8); // b*8 + h*4 + st
    int b = l >> 3, h = (l >> 2) & 1, st = l & 3;
    int tid = threadIdx.x, lane = tid & 63, wid = tid >> 6;
    int l15 = lane & 15;
    int n0 = st * 128 + wid * 32;
    int kb = (lane >> 4) * 8;

    f32x4 acc[4][2];
#pragma unroll
    for (int i = 0; i < 4; ++i)
#pragma unroll
        for (int j = 0; j < 2; ++j) acc[i][j] = (f32x4)0.f;

    const short* Aq = q_bf + (size_t)l15 * NH + h * DH + kb;
    const short* Bk = K_bf + ((size_t)b * SL + n0 + l15) * NH + h * DH + kb;

    short8 a0[4], a1[4];
    short8 b0[2], b1[2];
    ldg4(a0, Aq, 0, NH);
    ldg2(b0, Bk, 0, NH);
#pragma unroll
    for (int p = 0; p < 4; ++p) {
        int k1 = p * 64 + 32;
        ldg4(a1, Aq, k1, NH);
        ldg2(b1, Bk, k1, NH);
        mm42(acc, a0, b0);
        if (p < 3) {
            ldg4(a0, Aq, k1 + 32, NH);
            ldg2(b0, Bk, k1 + 32, NH);
        }
        mm42(acc, a1, b1);
    }

    int crow = (lane >> 4) * 4;
#pragma unroll
    for (int i = 0; i < 4; ++i)
#pragma unroll
        for (int j = 0; j < 2; ++j) {
            int col = n0 + j * 16 + l15;
#pragma unroll
            for (int r = 0; r < 4; ++r) {
                int row = i * 16 + crow + r;
                S_bf[(((size_t)(b * HEADS + h)) * NE + row) * SL + col] = f2b(acc[i][j][r]);
            }
        }
}

// ---------------------------------------------------------------------------
// attn_out: softmax -> PV -> out-GEMM, fused. Block = (slot n, e-half eh),
// 512 thr (8 waves = 2/SIMD). Softmax no-max, batched, register-resident.
// GEMM phases 2-deep pipelined; V iter-0 prefetched before softmax, Wo
// iter-0 before the ctx barrier (pinned with sched_barrier).
__global__ void __launch_bounds__(512, 2)
attn_out(const short* __restrict__ S_bf,
         const short* __restrict__ Vt_bf,
         const void* __restrict__ ents,
         const int* __restrict__ flag,
         const short* __restrict__ Wo_bf,
         const float* __restrict__ bo,
         float* __restrict__ out) {
    __shared__ short Pld[2 * 32 * SL]; // 64 KB
    int l = swz8(blockIdx.x, 32); // b*32 + ent*2 + eh
    int b = l >> 5;
    int ent = (l >> 1) & 15, eh = l & 1;
    int n = b * EN + ent;
    int tid = threadIdx.x, lane = tid & 63, wid = tid >> 6;
    int l15 = lane & 15;
    int kb = (lane >> 4) * 8;
    int crow = (lane >> 4) * 4;
    int h = wid >> 2, dq = wid & 3;

    // key-padding mask bits for s = lane*8 + j
    unsigned att8 = 0;
    {
        size_t mbase = ((size_t)b * EN + ent) * SL + lane * 8;
        if (flag[0]) {
            const int* p = (const int*)ents;
#pragma unroll
            for (int j = 0; j < 8; ++j)
                if (p[mbase + j]) att8 |= 1u << j;
        } else {
            const unsigned char* p = (const unsigned char*)ents;
#pragma unroll
            for (int j = 0; j < 8; ++j)
                if (p[mbase + j]) att8 |= 1u << j;
        }
    }

    // ---- early prefetch: PV iter-0 V loads (complete by the barrier) ----
    const short* Bv = Vt_bf + ((size_t)b * NH + h * DH + dq * 64 + l15) * SL + kb;
    short8 bvA[4], bvB[4];
    ldg4(bvA, Bv, 0, SL);
    __builtin_amdgcn_sched_barrier(0);

    // ---- Phase A: softmax (no max pass). wave w: head h, rows (w&3)*8.. ----
    {
        const short* Sbase =
            S_bf + (((size_t)(b * HEADS + h)) * NE + eh * 32 + (wid & 3) * 8) * SL + lane * 8;
        short8 sr[8];
#pragma unroll
        for (int it = 0; it < 8; ++it) sr[it] = *(const short8*)(Sbase + (size_t)it * SL);

        float pall[8][8];
        float sums[8];
#pragma unroll
        for (int it = 0; it < 8; ++it) {
            float s = 0.f;
#pragma unroll
            for (int j = 0; j < 8; ++j) {
                float v = (att8 >> j & 1) ? b2f(sr[it][j]) : -1e9f;
                float e = __expf(v);
                pall[it][j] = e;
                s += e;
            }
            sums[it] = s;
        }
        // interleaved butterflies: 8 independent chains per step
#pragma unroll
        for (int off = 32; off; off >>= 1)
#pragma unroll
            for (int it = 0; it < 8; ++it) sums[it] += __shfl_xor(sums[it], off);
#pragma unroll
        for (int it = 0; it < 8; ++it) {
            float iv = 1.f / sums[it];
            short8 pv;
#pragma unroll
            for (int j = 0; j < 8; ++j) pv[j] = f2b(pall[it][j] * iv);
            int el = (wid & 3) * 8 + it;
            *(short8*)&Pld[h * (32 * SL) + el * SL + ((lane ^ (el & 7)) * 8)] = pv;
        }
    }
    __syncthreads();

    // ---- Phase B: PV, 2-deep pipelined. wave (h, dq): 32 rows x 64 cols ----
    f32x4 acc[2][4];
#pragma unroll
    for (int i = 0; i < 2; ++i)
#pragma unroll
        for (int j = 0; j < 4; ++j) acc[i][j] = (f32x4)0.f;
    {
        const short* Ph = &Pld[h * (32 * SL)];
        short8 paA[2], paB[2];
        ldsw2(paA, Ph, 0, kb, l15);
#pragma unroll
        for (int p = 0; p < 8; ++p) {
            int k1 = p * 64 + 32;
            ldg4(bvB, Bv, k1, SL);
            ldsw2(paB, Ph, k1, kb, l15);
            mm24(acc, paA, bvA);
            if (p < 7) {
                ldg4(bvA, Bv, k1 + 32, SL);
                ldsw2(paA, Ph, k1 + 32, kb, l15);
            }
            mm24(acc, paB, bvB);
        }
    }
    __syncthreads();

    // ---- early prefetch: out-GEMM iter-0 Wo loads ----
    const short* Bw = Wo_bf + (size_t)(wid * 64 + l15) * NH + kb;
    short8 bwA[4], bwB[4];
    ldg4(bwA, Bw, 0, NH);
    __builtin_amdgcn_sched_barrier(0);

    // ---- Phase C: ctx -> LDS (reuse lower 32 KB; h0's P is dead) ----
#pragma unroll
    for (int i = 0; i < 2; ++i)
#pragma unroll
        for (int j = 0; j < 4; ++j) {
            int dg = h * DH + dq * 64 + j * 16 + l15; // 0..511
            int g = dg >> 3, cs = dg & 7;
#pragma unroll
            for (int r = 0; r < 4; ++r) {
                int el = i * 16 + crow + r;
                Pld[el * SL + ((g ^ (el & 7)) * 8) + cs] = f2b(acc[i][j][r]);
            }
        }
    __syncthreads();

    // ---- Phase D: out tile [32 x 512] = ctx @ Wo^T + bo, 2-deep pipelined ----
    {
        int n0 = wid * 64;
        f32x4 oacc[2][4];
#pragma unroll
        for (int i = 0; i < 2; ++i)
#pragma unroll
            for (int j = 0; j < 4; ++j) oacc[i][j] = (f32x4)0.f;

        short8 caA[2], caB[2];
        ldsw2(caA, Pld, 0, kb, l15);
#pragma unroll
        for (int p = 0; p < 8; ++p) {
            int k1 = p * 64 + 32;
            ldg4(bwB, Bw, k1, NH);
            ldsw2(caB, Pld, k1, kb, l15);
            mm24(oacc, caA, bwA);
            if (p < 7) {
                ldg4(bwA, Bw, k1 + 32, NH);
                ldsw2(caA, Pld, k1 + 32, kb, l15);
            }
            mm24(oacc, caB, bwB);
        }

        size_t rbase = (size_t)n * NE + eh * 32;
#pragma unroll
        for (int i = 0; i < 2; ++i)
#pragma unroll
            for (int j = 0; j < 4; ++j) {
                int col = n0 + j * 16 + l15;
                float bval = bo[col];
#pragma unroll
                for (int r = 0; r < 4; ++r) {
                    size_t row = rbase + i * 16 + crow + r;
                    out[row * NH + col] = oacc[i][j][r] + bval;
                }
            }
    }
}

// ---------------------------------------------------------------------------
extern "C" void kernel_launch(void* const* d_in, const int* in_sizes, int n_in,
                              void* d_out, int out_size, void* d_ws, size_t ws_size,
                              hipStream_t stream) {
    const float* toks = (const float*)d_in[0];
    const void* ents = d_in[1];
    const float* evs = (const float*)d_in[2];
    const float* Wq = (const float*)d_in[6];
    const float* Wk = (const float*)d_in[7];
    const float* Wv = (const float*)d_in[8];
    const float* bq = (const float*)d_in[9];
    const float* bk = (const float*)d_in[10];
    const float* bv = (const float*)d_in[11];
    const float* Wo = (const float*)d_in[12];
    const float* bo = (const float*)d_in[13];

    char* ws = (char*)d_ws;
    short* toks_bf = (short*)(ws + WS_TOKS);
    short* K_bf = (short*)(ws + WS_K);
    short* Vt_bf = (short*)(ws + WS_VT);
    short* S_bf = (short*)(ws + WS_S);
    short* Wk_bf = (short*)(ws + WS_WK);
    short* Wv_bf = (short*)(ws + WS_WV);
    short* Wo_bf = (short*)(ws + WS_WO);
    short* Wq_bf = (short*)(ws + WS_WQ);
    short* ev_bf = (short*)(ws + WS_EV);
    short* q_bf = (short*)(ws + WS_Q);
    int* flag = (int*)(ws + WS_FLAG);

    prep_kernel<<<CH_TOTAL / 256 + 1, 256, 0, stream>>>(
        toks, Wk, Wv, Wo, Wq, evs, (const unsigned char*)ents,
        toks_bf, Wk_bf, Wv_bf, Wo_bf, Wq_bf, ev_bf, flag);
    proj_kernel<<<260, 256, 0, stream>>>(toks_bf, Wk_bf, Wv_bf, ev_bf, Wq_bf,
                                         bk, bv, bq, K_bf, Vt_bf, q_bf);
    scores_mfma<<<64, 256, 0, stream>>>(q_bf, K_bf, S_bf);
    attn_out<<<256, 512, 0, stream>>>(S_bf, Vt_bf, ents, flag, Wo_bf, bo, (float*)d_out);
}